// Round 1
// baseline (1430.942 us; speedup 1.0000x reference)
//
#include <hip/hip_runtime.h>
#include <math.h>

// Problem constants (fixed by the reference)
#define SEQ   2048
#define DM    1024
#define NH    16
#define DH    64
#define DFF   4096

// ---------------------------------------------------------------------------
// Tiled fp32 GEMM: C[M,N] = A[M,K] @ W[N,K]^T + bias[N]  (+ residual) (+ReLU)
// 64x64 block tile, 256 threads, 4x4 micro-tile, BK=32.
// LDS stored transposed (As[k][m]) padded to 68 floats so float4 reads are
// 16B-aligned and near conflict-free.
// ---------------------------------------------------------------------------
template<bool RELU, bool RES>
__global__ __launch_bounds__(256) void gemm_k(
    const float* __restrict__ A,     // [M,K]
    const float* __restrict__ W,     // [N,K]
    const float* __restrict__ bias,  // [N]
    const float* __restrict__ res,   // [M,N] or nullptr
    float* __restrict__ C,           // [M,N]
    int M, int N, int K)
{
    __shared__ float As[32][68];
    __shared__ float Ws[32][68];

    const int t  = threadIdx.x;
    const int tx = t & 15;
    const int ty = t >> 4;
    const int m0 = blockIdx.y * 64;
    const int n0 = blockIdx.x * 64;

    float acc[4][4] = {};

    for (int k0 = 0; k0 < K; k0 += 32) {
        // Stage A and W tiles (64 rows x 32 k) into LDS, transposed.
        #pragma unroll
        for (int p = 0; p < 2; ++p) {
            int idx = t + p * 256;          // 0..511
            int row = idx >> 3;             // 0..63
            int kg  = (idx & 7) << 2;       // 0,4,...,28
            float4 a = *(const float4*)(A + (long)(m0 + row) * K + k0 + kg);
            As[kg + 0][row] = a.x; As[kg + 1][row] = a.y;
            As[kg + 2][row] = a.z; As[kg + 3][row] = a.w;
            float4 w = *(const float4*)(W + (long)(n0 + row) * K + k0 + kg);
            Ws[kg + 0][row] = w.x; Ws[kg + 1][row] = w.y;
            Ws[kg + 2][row] = w.z; Ws[kg + 3][row] = w.w;
        }
        __syncthreads();

        #pragma unroll
        for (int k = 0; k < 32; ++k) {
            float4 a4 = *(const float4*)&As[k][ty << 2];
            float4 b4 = *(const float4*)&Ws[k][tx << 2];
            float av[4] = {a4.x, a4.y, a4.z, a4.w};
            float bv[4] = {b4.x, b4.y, b4.z, b4.w};
            #pragma unroll
            for (int i = 0; i < 4; ++i)
                #pragma unroll
                for (int j = 0; j < 4; ++j)
                    acc[i][j] += av[i] * bv[j];
        }
        __syncthreads();
    }

    // Epilogue
    float4 bv = *(const float4*)(bias + n0 + (tx << 2));
    #pragma unroll
    for (int i = 0; i < 4; ++i) {
        int m = m0 + (ty << 2) + i;
        float4 o;
        o.x = acc[i][0] + bv.x;
        o.y = acc[i][1] + bv.y;
        o.z = acc[i][2] + bv.z;
        o.w = acc[i][3] + bv.w;
        if (RES) {
            float4 r = *(const float4*)(res + (long)m * N + n0 + (tx << 2));
            o.x += r.x; o.y += r.y; o.z += r.z; o.w += r.w;
        }
        if (RELU) {
            o.x = fmaxf(o.x, 0.f); o.y = fmaxf(o.y, 0.f);
            o.z = fmaxf(o.z, 0.f); o.w = fmaxf(o.w, 0.f);
        }
        *(float4*)(C + (long)m * N + n0 + (tx << 2)) = o;
    }
}

// ---------------------------------------------------------------------------
// Flash attention (non-causal), fp32. One block = one head x 32 query rows.
// 256 threads: thread t -> (r = t>>3) query row, (c = t&7) owns 8 cols.
// K tile stored transposed in LDS so the QK^T inner loop is vectorized.
// Online softmax (running max/sum), O accumulated in registers.
// ---------------------------------------------------------------------------
__global__ __launch_bounds__(256) void attn_k(
    const float* __restrict__ Q,   // [S, DM], col = h*DH + d
    const float* __restrict__ Kg,  // [S, DM]
    const float* __restrict__ Vg,  // [S, DM]
    float* __restrict__ O)         // [S, DM]
{
    __shared__ float Qs[32][68];   // query rows (pre-scaled by 1/8)
    __shared__ float Kt[64][68];   // transposed: Kt[d][key]
    __shared__ float Vs[64][68];   // row-major: Vs[key][d]
    __shared__ float Ps[32][68];   // probabilities for current key tile

    const int t  = threadIdx.x;
    const int h  = blockIdx.y;
    const int q0 = blockIdx.x * 32;
    const int r  = t >> 3;
    const int c  = t & 7;
    const int colbase = h * DH;

    // Load Q tile (scaled by 1/sqrt(DH) = 0.125)
    #pragma unroll
    for (int p = 0; p < 2; ++p) {
        int idx = t + p * 256;          // 0..511
        int row = idx >> 4;             // 0..31
        int cg  = (idx & 15) << 2;      // 0..60
        float4 q4 = *(const float4*)(Q + (long)(q0 + row) * DM + colbase + cg);
        Qs[row][cg + 0] = q4.x * 0.125f;
        Qs[row][cg + 1] = q4.y * 0.125f;
        Qs[row][cg + 2] = q4.z * 0.125f;
        Qs[row][cg + 3] = q4.w * 0.125f;
    }

    float m_run = -INFINITY;
    float l_run = 0.f;
    float o[8];
    #pragma unroll
    for (int j = 0; j < 8; ++j) o[j] = 0.f;

    for (int kb = 0; kb < SEQ; kb += 64) {
        __syncthreads();   // previous iteration's reads of Kt/Vs/Ps done
        #pragma unroll
        for (int p = 0; p < 4; ++p) {
            int idx = t + p * 256;      // 0..1023
            int row = idx >> 4;         // 0..63  (key index)
            int cg  = (idx & 15) << 2;  // 0..60  (d)
            float4 k4 = *(const float4*)(Kg + (long)(kb + row) * DM + colbase + cg);
            Kt[cg + 0][row] = k4.x; Kt[cg + 1][row] = k4.y;
            Kt[cg + 2][row] = k4.z; Kt[cg + 3][row] = k4.w;
            float4 v4 = *(const float4*)(Vg + (long)(kb + row) * DM + colbase + cg);
            Vs[row][cg + 0] = v4.x; Vs[row][cg + 1] = v4.y;
            Vs[row][cg + 2] = v4.z; Vs[row][cg + 3] = v4.w;
        }
        __syncthreads();

        // scores for this thread's 8 key columns (c*8 .. c*8+7)
        float sv[8];
        #pragma unroll
        for (int j = 0; j < 8; ++j) sv[j] = 0.f;
        #pragma unroll 8
        for (int d = 0; d < 64; ++d) {
            float qv = Qs[r][d];
            float4 k0 = *(const float4*)&Kt[d][c * 8];
            float4 k1 = *(const float4*)&Kt[d][c * 8 + 4];
            sv[0] += qv * k0.x; sv[1] += qv * k0.y;
            sv[2] += qv * k0.z; sv[3] += qv * k0.w;
            sv[4] += qv * k1.x; sv[5] += qv * k1.y;
            sv[6] += qv * k1.z; sv[7] += qv * k1.w;
        }

        // online softmax update across the 8 lanes of this row
        float mloc = sv[0];
        #pragma unroll
        for (int j = 1; j < 8; ++j) mloc = fmaxf(mloc, sv[j]);
        mloc = fmaxf(mloc, __shfl_xor(mloc, 1));
        mloc = fmaxf(mloc, __shfl_xor(mloc, 2));
        mloc = fmaxf(mloc, __shfl_xor(mloc, 4));
        float mnew  = fmaxf(m_run, mloc);
        float alpha = __expf(m_run - mnew);   // 0 on first iteration

        float p8[8];
        float ll = 0.f;
        #pragma unroll
        for (int j = 0; j < 8; ++j) { p8[j] = __expf(sv[j] - mnew); ll += p8[j]; }
        ll += __shfl_xor(ll, 1);
        ll += __shfl_xor(ll, 2);
        ll += __shfl_xor(ll, 4);

        l_run = l_run * alpha + ll;
        m_run = mnew;
        #pragma unroll
        for (int j = 0; j < 8; ++j) o[j] *= alpha;

        #pragma unroll
        for (int j = 0; j < 8; ++j) Ps[r][c * 8 + j] = p8[j];
        __syncthreads();

        // O += P @ V for this thread's 8 output columns
        #pragma unroll 8
        for (int kk = 0; kk < 64; ++kk) {
            float pv = Ps[r][kk];
            float4 v0 = *(const float4*)&Vs[kk][c * 8];
            float4 v1 = *(const float4*)&Vs[kk][c * 8 + 4];
            o[0] += pv * v0.x; o[1] += pv * v0.y;
            o[2] += pv * v0.z; o[3] += pv * v0.w;
            o[4] += pv * v1.x; o[5] += pv * v1.y;
            o[6] += pv * v1.z; o[7] += pv * v1.w;
        }
    }

    float inv = 1.f / l_run;
    #pragma unroll
    for (int j = 0; j < 8; ++j)
        O[(long)(q0 + r) * DM + colbase + c * 8 + j] = o[j] * inv;
}

// ---------------------------------------------------------------------------
// LayerNorm over last dim (1024). One block (256 threads) per row.
// Input is the already-summed (residual-added) tensor.
// ---------------------------------------------------------------------------
__global__ __launch_bounds__(256) void ln_k(
    const float* __restrict__ X,  // [S, DM]
    const float* __restrict__ g,
    const float* __restrict__ b,
    float* __restrict__ out)      // [S, DM]
{
    const int row = blockIdx.x;
    const int t   = threadIdx.x;
    const float* xr = X + (long)row * DM;

    float4 v = *(const float4*)(xr + (t << 2));
    float s1 = v.x + v.y + v.z + v.w;
    float s2 = v.x * v.x + v.y * v.y + v.z * v.z + v.w * v.w;
    #pragma unroll
    for (int off = 32; off > 0; off >>= 1) {
        s1 += __shfl_xor(s1, off);
        s2 += __shfl_xor(s2, off);
    }
    __shared__ float red[8];
    int wid = t >> 6, lid = t & 63;
    if (lid == 0) { red[wid] = s1; red[4 + wid] = s2; }
    __syncthreads();
    s1 = red[0] + red[1] + red[2] + red[3];
    s2 = red[4] + red[5] + red[6] + red[7];

    float mu   = s1 * (1.f / DM);
    float var  = s2 * (1.f / DM) - mu * mu;
    float rstd = rsqrtf(var + 1e-5f);

    float4 gv = *(const float4*)(g + (t << 2));
    float4 bv = *(const float4*)(b + (t << 2));
    float4 ov;
    ov.x = (v.x - mu) * rstd * gv.x + bv.x;
    ov.y = (v.y - mu) * rstd * gv.y + bv.y;
    ov.z = (v.z - mu) * rstd * gv.z + bv.z;
    ov.w = (v.w - mu) * rstd * gv.w + bv.w;
    *(float4*)(out + (long)row * DM + (t << 2)) = ov;
}

// ---------------------------------------------------------------------------
extern "C" void kernel_launch(void* const* d_in, const int* in_sizes, int n_in,
                              void* d_out, int out_size, void* d_ws, size_t ws_size,
                              hipStream_t stream)
{
    const float* x       = (const float*)d_in[0];
    const float* q_in_w  = (const float*)d_in[1];
    const float* q_in_b  = (const float*)d_in[2];
    const float* k_in_w  = (const float*)d_in[3];
    const float* k_in_b  = (const float*)d_in[4];
    const float* v_in_w  = (const float*)d_in[5];
    const float* v_in_b  = (const float*)d_in[6];
    const float* out_w   = (const float*)d_in[7];
    const float* out_b   = (const float*)d_in[8];
    const float* ffn1_w  = (const float*)d_in[9];
    const float* ffn1_b  = (const float*)d_in[10];
    const float* ffn2_w  = (const float*)d_in[11];
    const float* ffn2_b  = (const float*)d_in[12];
    const float* n1_g    = (const float*)d_in[13];
    const float* n1_b    = (const float*)d_in[14];
    const float* n2_g    = (const float*)d_in[15];
    const float* n2_b    = (const float*)d_in[16];
    const float* q_out_w = (const float*)d_in[17];
    const float* q_out_b = (const float*)d_in[18];
    const float* k_out_w = (const float*)d_in[19];
    const float* k_out_b = (const float*)d_in[20];
    const float* v_out_w = (const float*)d_in[21];
    const float* v_out_b = (const float*)d_in[22];
    // d_in[23] = seq_length (2048, hardcoded)

    float* out = (float*)d_out;
    const long SD = (long)SEQ * DM;

    // Workspace layout (floats). Total needed: 6*SD = 48 MB.
    //   [0,3SD)  q/k/v in-proj buffers, later reused by f1 (needs 4SD=[0,4SD))
    //   [3SD,4SD) attn output, dead before f1 is written
    //   [4SD,5SD) tmp (pre-LN1 sum), reused as tmp2 (pre-LN2 sum)
    //   [5SD,6SD) h (LN1 output)
    float* ws   = (float*)d_ws;
    float* qb   = ws;
    float* kb   = ws + SD;
    float* vb   = ws + 2 * SD;
    float* attn = ws + 3 * SD;
    float* tmp  = ws + 4 * SD;
    float* h    = ws + 5 * SD;
    float* f1   = ws;            // [SEQ, DFF] = 4*SD floats, reuses qb..attn
    float* tmp2 = ws + 4 * SD;   // reuses tmp
    float* y    = out + 3 * SD;  // 4th output

    dim3 blk(256);
    dim3 gD (DM  / 64, SEQ / 64);   // 16 x 32
    dim3 gFF(DFF / 64, SEQ / 64);   // 64 x 32

    // in-projections
    gemm_k<false, false><<<gD, blk, 0, stream>>>(x, q_in_w, q_in_b, nullptr, qb, SEQ, DM, DM);
    gemm_k<false, false><<<gD, blk, 0, stream>>>(x, k_in_w, k_in_b, nullptr, kb, SEQ, DM, DM);
    gemm_k<false, false><<<gD, blk, 0, stream>>>(x, v_in_w, v_in_b, nullptr, vb, SEQ, DM, DM);

    // attention
    attn_k<<<dim3(SEQ / 32, NH), blk, 0, stream>>>(qb, kb, vb, attn);

    // out-projection + residual, then LN1
    gemm_k<false, true><<<gD, blk, 0, stream>>>(attn, out_w, out_b, x, tmp, SEQ, DM, DM);
    ln_k<<<SEQ, blk, 0, stream>>>(tmp, n1_g, n1_b, h);

    // FFN
    gemm_k<true,  false><<<gFF, blk, 0, stream>>>(h,  ffn1_w, ffn1_b, nullptr, f1,   SEQ, DFF, DM);
    gemm_k<false, true ><<<gD,  blk, 0, stream>>>(f1, ffn2_w, ffn2_b, h,       tmp2, SEQ, DM, DFF);
    ln_k<<<SEQ, blk, 0, stream>>>(tmp2, n2_g, n2_b, y);

    // next-layer projections
    gemm_k<false, false><<<gD, blk, 0, stream>>>(y, q_out_w, q_out_b, nullptr, out,          SEQ, DM, DM);
    gemm_k<false, false><<<gD, blk, 0, stream>>>(y, k_out_w, k_out_b, nullptr, out + SD,     SEQ, DM, DM);
    gemm_k<false, false><<<gD, blk, 0, stream>>>(y, v_out_w, v_out_b, nullptr, out + 2 * SD, SEQ, DM, DM);
}

// Round 3
// 488.961 us; speedup vs baseline: 2.9265x; 2.9265x over previous
//
#include <hip/hip_runtime.h>
#include <math.h>

#define SEQ   2048
#define DM    1024
#define NH    16
#define DH    64
#define DFF   4096

typedef __bf16 bf16;
using bf16x8 = __attribute__((ext_vector_type(8))) __bf16;
using f32x4  = __attribute__((ext_vector_type(4))) float;

__device__ __forceinline__ unsigned short f2bfu(float f) {
    unsigned int u = __float_as_uint(f);
    u += 0x7FFF + ((u >> 16) & 1);          // round-to-nearest-even
    return (unsigned short)(u >> 16);
}
__device__ __forceinline__ bf16 f2bf(float f) {
    unsigned short s = f2bfu(f);
    return __builtin_bit_cast(bf16, s);
}

// ---------------------------------------------------------------------------
// fp32 -> bf16 conversion, 4 elems/thread
// ---------------------------------------------------------------------------
__global__ __launch_bounds__(256) void conv_k(const float* __restrict__ src,
                                              bf16* __restrict__ dst, int n) {
    int i = (blockIdx.x * 256 + threadIdx.x) * 4;
    if (i >= n) return;
    float4 v = *(const float4*)(src + i);
    ushort4 o;
    o.x = f2bfu(v.x); o.y = f2bfu(v.y); o.z = f2bfu(v.z); o.w = f2bfu(v.w);
    *(ushort4*)((unsigned short*)dst + i) = o;
}

// ---------------------------------------------------------------------------
// bf16 MFMA GEMM: C[M,N] = A[M,K] @ W[N,K]^T + bias (+res fp32) (+relu)
// Block tile 128 x BN, 256 threads = 4 waves (2x2), BK=32.
// LDS layout As[kquad][row][8]: fragment read = ds_read_b128, contiguous
// 256B per 16 lanes (2-way wave aliasing = free, m136).
// z batches up to 3 weight/output sets sharing A (q/k/v projections).
// ---------------------------------------------------------------------------
struct GemmPtrs {
    const bf16* W[3];
    const float* bias[3];
    float* out32[3];
    bf16*  out16[3];
};

template<int BN>
__global__ __launch_bounds__(256) void gemm_bf16_k(
    const bf16* __restrict__ A, const float* __restrict__ res,
    GemmPtrs p, int N, int K, int relu)
{
    constexpr int WN = BN / 2;
    constexpr int TN = BN / 32;
    __shared__ bf16 As[4][128][8];
    __shared__ bf16 Ws[4][BN][8];

    const int t    = threadIdx.x;
    const int lane = t & 63;
    const int wave = t >> 6;
    const int quad = lane >> 4;
    const int l15  = lane & 15;
    const int wm   = (wave >> 1) * 64;
    const int wn   = (wave & 1) * WN;
    const int m0   = blockIdx.y * 128;
    const int n0   = blockIdx.x * BN;
    const int z    = blockIdx.z;
    const bf16* __restrict__ W = p.W[z];

    f32x4 acc[4][TN];
    #pragma unroll
    for (int i = 0; i < 4; ++i)
        #pragma unroll
        for (int j = 0; j < TN; ++j)
            acc[i][j] = f32x4{0.f, 0.f, 0.f, 0.f};

    for (int k0 = 0; k0 < K; k0 += 32) {
        #pragma unroll
        for (int s = 0; s < 2; ++s) {
            int idx = t + s * 256;
            int row = idx >> 2, kg = idx & 3;
            *(uint4*)&As[kg][row][0] =
                *(const uint4*)(A + (long)(m0 + row) * K + k0 + kg * 8);
        }
        #pragma unroll
        for (int s = 0; s < BN / 64; ++s) {
            int idx = t + s * 256;
            int row = idx >> 2, kg = idx & 3;
            *(uint4*)&Ws[kg][row][0] =
                *(const uint4*)(W + (long)(n0 + row) * K + k0 + kg * 8);
        }
        __syncthreads();

        bf16x8 a[4], b[TN];
        #pragma unroll
        for (int i = 0; i < 4; ++i)
            a[i] = *(const bf16x8*)&As[quad][wm + i * 16 + l15][0];
        #pragma unroll
        for (int j = 0; j < TN; ++j)
            b[j] = *(const bf16x8*)&Ws[quad][wn + j * 16 + l15][0];
        #pragma unroll
        for (int i = 0; i < 4; ++i)
            #pragma unroll
            for (int j = 0; j < TN; ++j)
                acc[i][j] = __builtin_amdgcn_mfma_f32_16x16x32_bf16(
                    a[i], b[j], acc[i][j], 0, 0, 0);
        __syncthreads();
    }

    // epilogue: D lane map row = quad*4+r, col = l15 (per 16x16 tile)
    float* o32 = p.out32[z];
    bf16*  o16 = p.out16[z];
    const float* bias = p.bias[z];
    #pragma unroll
    for (int j = 0; j < TN; ++j) {
        int n = n0 + wn + j * 16 + l15;
        float bv = bias[n];
        #pragma unroll
        for (int i = 0; i < 4; ++i) {
            #pragma unroll
            for (int r = 0; r < 4; ++r) {
                int m = m0 + wm + i * 16 + quad * 4 + r;
                float v = acc[i][j][r] + bv;
                if (res)  v += res[(long)m * N + n];
                if (relu) v = fmaxf(v, 0.f);
                if (o32) o32[(long)m * N + n] = v;
                if (o16) o16[(long)m * N + n] = f2bf(v);
            }
        }
    }
}

// ---------------------------------------------------------------------------
// Flash attention, bf16 MFMA. Block = 1 head x 64 q rows; 4 waves x 16 rows.
// QK^T and PV via mfma_f32_16x16x32_bf16; P converts C-layout -> A-layout
// through a per-wave LDS tile (m120 pattern). Online softmax in fp32.
// ---------------------------------------------------------------------------
__global__ __launch_bounds__(256) void attn_mfma_k(
    const bf16* __restrict__ Q, const bf16* __restrict__ K,
    const bf16* __restrict__ V, bf16* __restrict__ O)
{
    __shared__ bf16 Kb[64][72];     // [key][d]   stride 144 B (16B-aligned)
    __shared__ bf16 Vt[64][72];     // [d][key]   transposed
    __shared__ bf16 Pw[4][16][72];  // per-wave P tile [qrow][key]

    const int t    = threadIdx.x;
    const int lane = t & 63;
    const int wave = t >> 6;
    const int quad = lane >> 4;
    const int l15  = lane & 15;
    const int h    = blockIdx.y;
    const int q0   = blockIdx.x * 64;
    const int cb   = h * DH;

    // Q fragments (A-operand): lane holds Q[q0+wave*16+l15][kh*32+quad*8+j]
    const int qrow = q0 + wave * 16 + l15;
    bf16x8 aQ[2];
    #pragma unroll
    for (int kh = 0; kh < 2; ++kh)
        aQ[kh] = *(const bf16x8*)(Q + (long)qrow * DM + cb + kh * 32 + quad * 8);

    float m_run[4], l_run[4];
    f32x4 o_acc[4];
    #pragma unroll
    for (int r = 0; r < 4; ++r) { m_run[r] = -INFINITY; l_run[r] = 0.f; }
    #pragma unroll
    for (int dt = 0; dt < 4; ++dt) o_acc[dt] = f32x4{0.f, 0.f, 0.f, 0.f};

    for (int kv0 = 0; kv0 < SEQ; kv0 += 64) {
        __syncthreads();   // prior iteration's reads of Kb/Vt/Pw complete
        #pragma unroll
        for (int s = 0; s < 2; ++s) {
            int idx = t + s * 256;        // 0..511
            int key = idx >> 3;           // 0..63
            int dg  = idx & 7;            // 8-elem d-group
            *(uint4*)&Kb[key][dg * 8] =
                *(const uint4*)(K + (long)(kv0 + key) * DM + cb + dg * 8);
            bf16x8 vv = *(const bf16x8*)(V + (long)(kv0 + key) * DM + cb + dg * 8);
            #pragma unroll
            for (int j = 0; j < 8; ++j) Vt[dg * 8 + j][key] = vv[j];
        }
        __syncthreads();

        // ---- QK^T: scores S[row=quad*4+r][key=kt*16+l15] ----
        f32x4 s[4];
        #pragma unroll
        for (int kt = 0; kt < 4; ++kt) {
            s[kt] = f32x4{0.f, 0.f, 0.f, 0.f};
            bf16x8 b0 = *(const bf16x8*)&Kb[kt * 16 + l15][quad * 8];
            bf16x8 b1 = *(const bf16x8*)&Kb[kt * 16 + l15][32 + quad * 8];
            s[kt] = __builtin_amdgcn_mfma_f32_16x16x32_bf16(aQ[0], b0, s[kt], 0, 0, 0);
            s[kt] = __builtin_amdgcn_mfma_f32_16x16x32_bf16(aQ[1], b1, s[kt], 0, 0, 0);
        }

        // ---- online softmax (rows owned: quad*4+r, 16 lanes share a row) ----
        float pReg[4][4], alpha[4];
        #pragma unroll
        for (int r = 0; r < 4; ++r) {
            float mx = fmaxf(fmaxf(s[0][r], s[1][r]), fmaxf(s[2][r], s[3][r])) * 0.125f;
            mx = fmaxf(mx, __shfl_xor(mx, 1));
            mx = fmaxf(mx, __shfl_xor(mx, 2));
            mx = fmaxf(mx, __shfl_xor(mx, 4));
            mx = fmaxf(mx, __shfl_xor(mx, 8));
            float mnew = fmaxf(m_run[r], mx);
            alpha[r] = __expf(m_run[r] - mnew);
            m_run[r] = mnew;
            float ls = 0.f;
            #pragma unroll
            for (int kt = 0; kt < 4; ++kt) {
                float pv = __expf(s[kt][r] * 0.125f - mnew);
                pReg[kt][r] = pv;
                ls += pv;
            }
            ls += __shfl_xor(ls, 1);
            ls += __shfl_xor(ls, 2);
            ls += __shfl_xor(ls, 4);
            ls += __shfl_xor(ls, 8);
            l_run[r] = l_run[r] * alpha[r] + ls;
        }
        #pragma unroll
        for (int dt = 0; dt < 4; ++dt)
            #pragma unroll
            for (int r = 0; r < 4; ++r)
                o_acc[dt][r] *= alpha[r];

        // ---- P: C-layout -> LDS -> A-layout ----
        #pragma unroll
        for (int kt = 0; kt < 4; ++kt)
            #pragma unroll
            for (int r = 0; r < 4; ++r)
                Pw[wave][quad * 4 + r][kt * 16 + l15] = f2bf(pReg[kt][r]);
        __syncthreads();

        bf16x8 aP[2];
        #pragma unroll
        for (int kh = 0; kh < 2; ++kh)
            aP[kh] = *(const bf16x8*)&Pw[wave][l15][kh * 32 + quad * 8];

        // ---- PV: O[row][d=dt*16+l15] ----
        #pragma unroll
        for (int dt = 0; dt < 4; ++dt) {
            bf16x8 v0 = *(const bf16x8*)&Vt[dt * 16 + l15][quad * 8];
            bf16x8 v1 = *(const bf16x8*)&Vt[dt * 16 + l15][32 + quad * 8];
            o_acc[dt] = __builtin_amdgcn_mfma_f32_16x16x32_bf16(aP[0], v0, o_acc[dt], 0, 0, 0);
            o_acc[dt] = __builtin_amdgcn_mfma_f32_16x16x32_bf16(aP[1], v1, o_acc[dt], 0, 0, 0);
        }
    }

    #pragma unroll
    for (int r = 0; r < 4; ++r) {
        float inv = 1.f / l_run[r];
        int row = q0 + wave * 16 + quad * 4 + r;
        #pragma unroll
        for (int dt = 0; dt < 4; ++dt)
            O[(long)row * DM + cb + dt * 16 + l15] = f2bf(o_acc[dt][r] * inv);
    }
}

// ---------------------------------------------------------------------------
// LayerNorm over last dim (1024), one block/row. In-place safe: each thread
// reads exactly the float4 it later writes. fp32 out + optional bf16 copy.
// ---------------------------------------------------------------------------
__global__ __launch_bounds__(256) void ln_k(
    const float* __restrict__ X, const float* __restrict__ g,
    const float* __restrict__ b, float* __restrict__ out,
    bf16* __restrict__ out16)
{
    const int row = blockIdx.x;
    const int t   = threadIdx.x;
    const float* xr = X + (long)row * DM;

    float4 v = *(const float4*)(xr + (t << 2));
    float s1 = v.x + v.y + v.z + v.w;
    float s2 = v.x * v.x + v.y * v.y + v.z * v.z + v.w * v.w;
    #pragma unroll
    for (int off = 32; off > 0; off >>= 1) {
        s1 += __shfl_xor(s1, off);
        s2 += __shfl_xor(s2, off);
    }
    __shared__ float red[8];
    int wid = t >> 6, lid = t & 63;
    if (lid == 0) { red[wid] = s1; red[4 + wid] = s2; }
    __syncthreads();
    s1 = red[0] + red[1] + red[2] + red[3];
    s2 = red[4] + red[5] + red[6] + red[7];

    float mu   = s1 * (1.f / DM);
    float var  = s2 * (1.f / DM) - mu * mu;
    float rstd = rsqrtf(var + 1e-5f);

    float4 gv = *(const float4*)(g + (t << 2));
    float4 bv = *(const float4*)(b + (t << 2));
    float4 ov;
    ov.x = (v.x - mu) * rstd * gv.x + bv.x;
    ov.y = (v.y - mu) * rstd * gv.y + bv.y;
    ov.z = (v.z - mu) * rstd * gv.z + bv.z;
    ov.w = (v.w - mu) * rstd * gv.w + bv.w;
    *(float4*)(out + (long)row * DM + (t << 2)) = ov;
    if (out16) {
        ushort4 o;
        o.x = f2bfu(ov.x); o.y = f2bfu(ov.y); o.z = f2bfu(ov.z); o.w = f2bfu(ov.w);
        *(ushort4*)((unsigned short*)out16 + (long)row * DM + (t << 2)) = o;
    }
}

// ---------------------------------------------------------------------------
extern "C" void kernel_launch(void* const* d_in, const int* in_sizes, int n_in,
                              void* d_out, int out_size, void* d_ws, size_t ws_size,
                              hipStream_t stream)
{
    const float* x       = (const float*)d_in[0];
    const float* q_in_w  = (const float*)d_in[1];
    const float* q_in_b  = (const float*)d_in[2];
    const float* k_in_w  = (const float*)d_in[3];
    const float* k_in_b  = (const float*)d_in[4];
    const float* v_in_w  = (const float*)d_in[5];
    const float* v_in_b  = (const float*)d_in[6];
    const float* out_w   = (const float*)d_in[7];
    const float* out_b   = (const float*)d_in[8];
    const float* ffn1_w  = (const float*)d_in[9];
    const float* ffn1_b  = (const float*)d_in[10];
    const float* ffn2_w  = (const float*)d_in[11];
    const float* ffn2_b  = (const float*)d_in[12];
    const float* n1_g    = (const float*)d_in[13];
    const float* n1_b    = (const float*)d_in[14];
    const float* n2_g    = (const float*)d_in[15];
    const float* n2_b    = (const float*)d_in[16];
    const float* q_out_w = (const float*)d_in[17];
    const float* q_out_b = (const float*)d_in[18];
    const float* k_out_w = (const float*)d_in[19];
    const float* k_out_b = (const float*)d_in[20];
    const float* v_out_w = (const float*)d_in[21];
    const float* v_out_b = (const float*)d_in[22];

    float* out = (float*)d_out;
    const long SD = (long)SEQ * DM;           // 2 M elements
    const long MB = 1024 * 1024;

    // --- workspace layout: 48 MiB total (== proven round-1 usage) ---
    // [0,4)    xbf, later ybf                     (bf16 activations)
    // [4,20)   qb/kb/vb/atnb, later f1 [S,DFF]
    // [20,28)  tmp fp32: pre-LN1 sum -> LN1 output h32 (in-place)
    // [28,32)  h16
    // [32,40)  wqi/wki/wvi/wo, later wf2          (recycled mid-stream)
    // [40,48)  wf1, later wqo/wko/wvo             (recycled mid-stream)
    char* w = (char*)d_ws;
    bf16* xbf   = (bf16*)(w);
    bf16* qb    = (bf16*)(w + 4  * MB);
    bf16* kb    = (bf16*)(w + 8  * MB);
    bf16* vb    = (bf16*)(w + 12 * MB);
    bf16* atnb  = (bf16*)(w + 16 * MB);
    bf16* f1    = (bf16*)(w + 4  * MB);       // overlays qb..atnb (dead)
    float* tmp  = (float*)(w + 20 * MB);      // pre-LN1, then h32 in-place
    bf16* h16   = (bf16*)(w + 28 * MB);
    bf16* wqi   = (bf16*)(w + 32 * MB);
    bf16* wki   = (bf16*)(w + 34 * MB);
    bf16* wvi   = (bf16*)(w + 36 * MB);
    bf16* wo    = (bf16*)(w + 38 * MB);
    bf16* wf2   = (bf16*)(w + 32 * MB);       // overlays wqi..wo (dead)
    bf16* wf1   = (bf16*)(w + 40 * MB);
    bf16* wqo   = (bf16*)(w + 40 * MB);       // overlays wf1 (dead)
    bf16* wko   = (bf16*)(w + 42 * MB);
    bf16* wvo   = (bf16*)(w + 44 * MB);
    bf16* ybf   = (bf16*)(w);                 // overlays xbf (dead)
    float* y32  = out + 3 * SD;               // pre-LN2 staged in d_out, LN2 in-place

    dim3 blk(256);
    const int DD = DM * DM;       // 1 M
    auto conv = [&](const float* s, bf16* d, int n) {
        conv_k<<<dim3(n / 1024), blk, 0, stream>>>(s, d, n);
    };

    // --- initial fp32 -> bf16 conversions ---
    conv(x, xbf, (int)SD);
    conv(q_in_w, wqi, DD);  conv(k_in_w, wki, DD);  conv(v_in_w, wvi, DD);
    conv(out_w, wo, DD);
    conv(ffn1_w, wf1, DM * DFF);

    // --- q/k/v in-projections (z-batched) ---
    {
        GemmPtrs p{};
        p.W[0] = wqi; p.W[1] = wki; p.W[2] = wvi;
        p.bias[0] = q_in_b; p.bias[1] = k_in_b; p.bias[2] = v_in_b;
        p.out16[0] = qb; p.out16[1] = kb; p.out16[2] = vb;
        gemm_bf16_k<64><<<dim3(DM / 64, SEQ / 128, 3), blk, 0, stream>>>(
            xbf, nullptr, p, DM, DM, 0);
    }

    // --- attention ---
    attn_mfma_k<<<dim3(SEQ / 64, NH), blk, 0, stream>>>(qb, kb, vb, atnb);

    // --- out-projection + residual(x) -> tmp ---
    {
        GemmPtrs p{};
        p.W[0] = wo; p.bias[0] = out_b; p.out32[0] = tmp;
        gemm_bf16_k<64><<<dim3(DM / 64, SEQ / 128, 1), blk, 0, stream>>>(
            atnb, x, p, DM, DM, 0);
    }
    // wqi..wo now dead -> stage wf2 in their place (stream-ordered)
    conv(ffn2_w, wf2, DM * DFF);

    ln_k<<<SEQ, blk, 0, stream>>>(tmp, n1_g, n1_b, tmp, h16);   // in-place

    // --- FFN ---
    {
        GemmPtrs p{};
        p.W[0] = wf1; p.bias[0] = ffn1_b; p.out16[0] = f1;
        gemm_bf16_k<128><<<dim3(DFF / 128, SEQ / 128, 1), blk, 0, stream>>>(
            h16, nullptr, p, DFF, DM, 1);
    }
    // wf1 now dead -> stage next-layer weights in its place
    conv(q_out_w, wqo, DD); conv(k_out_w, wko, DD); conv(v_out_w, wvo, DD);
    {
        GemmPtrs p{};
        p.W[0] = wf2; p.bias[0] = ffn2_b; p.out32[0] = y32;
        gemm_bf16_k<64><<<dim3(DM / 64, SEQ / 128, 1), blk, 0, stream>>>(
            f1, tmp, p, DM, DFF, 0);
    }
    ln_k<<<SEQ, blk, 0, stream>>>(y32, n2_g, n2_b, y32, ybf);   // in-place

    // --- next-layer projections (z-batched) ---
    {
        GemmPtrs p{};
        p.W[0] = wqo; p.W[1] = wko; p.W[2] = wvo;
        p.bias[0] = q_out_b; p.bias[1] = k_out_b; p.bias[2] = v_out_b;
        p.out32[0] = out; p.out32[1] = out + SD; p.out32[2] = out + 2 * SD;
        gemm_bf16_k<64><<<dim3(DM / 64, SEQ / 128, 3), blk, 0, stream>>>(
            ybf, nullptr, p, DM, DM, 0);
    }
}

// Round 4
// 448.489 us; speedup vs baseline: 3.1906x; 1.0902x over previous
//
#include <hip/hip_runtime.h>
#include <math.h>

#define SEQ   2048
#define DM    1024
#define NH    16
#define DH    64
#define DFF   4096

typedef __bf16 bf16;
using bf16x8 = __attribute__((ext_vector_type(8))) __bf16;
using f32x4  = __attribute__((ext_vector_type(4))) float;

__device__ __forceinline__ unsigned short f2bfu(float f) {
    unsigned int u = __float_as_uint(f);
    u += 0x7FFF + ((u >> 16) & 1);          // round-to-nearest-even
    return (unsigned short)(u >> 16);
}
__device__ __forceinline__ bf16 f2bf(float f) {
    unsigned short s = f2bfu(f);
    return __builtin_bit_cast(bf16, s);
}

// async global->LDS, 16B per lane. lds base must be wave-uniform; HW adds
// lane*16. Global address is per-lane.
__device__ __forceinline__ void gll16(const bf16* g, bf16* lds_base) {
    __builtin_amdgcn_global_load_lds(
        (const __attribute__((address_space(1))) unsigned int*)g,
        (__attribute__((address_space(3))) unsigned int*)lds_base, 16, 0, 0);
}

// ---------------------------------------------------------------------------
// fp32 -> bf16 conversion, 4 elems/thread
// ---------------------------------------------------------------------------
__global__ __launch_bounds__(256) void conv_k(const float* __restrict__ src,
                                              bf16* __restrict__ dst, int n) {
    int i = (blockIdx.x * 256 + threadIdx.x) * 4;
    if (i >= n) return;
    float4 v = *(const float4*)(src + i);
    ushort4 o;
    o.x = f2bfu(v.x); o.y = f2bfu(v.y); o.z = f2bfu(v.z); o.w = f2bfu(v.w);
    *(ushort4*)((unsigned short*)dst + i) = o;
}

// ---------------------------------------------------------------------------
// bf16 MFMA GEMM: C[M,N] = A[M,K] @ W[N,K]^T + bias (+res fp32) (+relu)
// Block tile BM x BN, 256 threads = 4 waves (2x2). BK=32.
// LDS natural [row][32] layout (64 B rows): global_load_lds dest is
// lane-linear; fragment ds_read_b128 is bank-conflict-free.
// ---------------------------------------------------------------------------
struct GemmPtrs {
    const bf16* W[3];
    const float* bias[3];
    float* out32[3];
    bf16*  out16[3];
};

template<int BM, int BN>
__global__ __launch_bounds__(256) void gemm_bf16_k(
    const bf16* __restrict__ A, const float* __restrict__ res,
    GemmPtrs p, int N, int K, int relu)
{
    constexpr int TM = BM / 32;
    constexpr int TN = BN / 32;
    __shared__ bf16 As[BM][32];
    __shared__ bf16 Ws[BN][32];

    const int t    = threadIdx.x;
    const int lane = t & 63;
    const int wave = t >> 6;
    const int quad = lane >> 4;
    const int l15  = lane & 15;
    const int wm   = (wave >> 1) * (BM / 2);
    const int wn   = (wave & 1) * (BN / 2);
    const int m0   = blockIdx.y * BM;
    const int n0   = blockIdx.x * BN;
    const bf16* __restrict__ W = p.W[blockIdx.z];

    f32x4 acc[TM][TN];
    #pragma unroll
    for (int i = 0; i < TM; ++i)
        #pragma unroll
        for (int j = 0; j < TN; ++j)
            acc[i][j] = f32x4{0.f, 0.f, 0.f, 0.f};

    for (int k0 = 0; k0 < K; k0 += 32) {
        #pragma unroll
        for (int s = 0; s < BM / 64; ++s) {
            int base = s * 256 + wave * 64;
            int idx  = base + lane;
            gll16(A + (long)(m0 + (idx >> 2)) * K + k0 + (idx & 3) * 8,
                  &As[0][0] + (long)base * 8);
        }
        #pragma unroll
        for (int s = 0; s < BN / 64; ++s) {
            int base = s * 256 + wave * 64;
            int idx  = base + lane;
            gll16(W + (long)(n0 + (idx >> 2)) * K + k0 + (idx & 3) * 8,
                  &Ws[0][0] + (long)base * 8);
        }
        __syncthreads();   // drains vmcnt (global_load_lds) for all waves

        bf16x8 a[TM], b[TN];
        #pragma unroll
        for (int i = 0; i < TM; ++i)
            a[i] = *(const bf16x8*)&As[wm + i * 16 + l15][quad * 8];
        #pragma unroll
        for (int j = 0; j < TN; ++j)
            b[j] = *(const bf16x8*)&Ws[wn + j * 16 + l15][quad * 8];
        #pragma unroll
        for (int i = 0; i < TM; ++i)
            #pragma unroll
            for (int j = 0; j < TN; ++j)
                acc[i][j] = __builtin_amdgcn_mfma_f32_16x16x32_bf16(
                    a[i], b[j], acc[i][j], 0, 0, 0);
        __syncthreads();
    }

    // epilogue: D lane map row = quad*4+r, col = l15 (per 16x16 tile)
    float* o32 = p.out32[blockIdx.z];
    bf16*  o16 = p.out16[blockIdx.z];
    const float* bias = p.bias[blockIdx.z];
    #pragma unroll
    for (int j = 0; j < TN; ++j) {
        int n = n0 + wn + j * 16 + l15;
        float bv = bias[n];
        #pragma unroll
        for (int i = 0; i < TM; ++i) {
            #pragma unroll
            for (int r = 0; r < 4; ++r) {
                int m = m0 + wm + i * 16 + quad * 4 + r;
                float v = acc[i][j][r] + bv;
                if (res)  v += res[(long)m * N + n];
                if (relu) v = fmaxf(v, 0.f);
                if (o32) o32[(long)m * N + n] = v;
                if (o16) o16[(long)m * N + n] = f2bf(v);
            }
        }
    }
}

// ---------------------------------------------------------------------------
// Flash attention, bf16 MFMA, fixed-max softmax (exact: p=exp(s/8), O=Pv/l).
// Block = 1 head x 64 q rows, 4 waves x 16 rows. Grid 32x16 = 512 blocks.
// Row sums l via MFMA against a ones-column B fragment (no shuffles in loop).
// Vt XOR-swizzled (key ^ dg*8, stride 72) -> conflict-free transpose store
// and b128 fragment read. Pw per-wave (no block barrier for P round-trip).
// ---------------------------------------------------------------------------
__global__ __launch_bounds__(256) void attn_mfma_k(
    const bf16* __restrict__ Q, const bf16* __restrict__ Kg,
    const bf16* __restrict__ Vg, bf16* __restrict__ O)
{
    __shared__ bf16 Kb[64][72];      // [key][d], stride 144 B
    __shared__ bf16 Vt[64][72];      // [d][key^swz], stride 144 B
    __shared__ bf16 Pw[4][16][76];   // per-wave P, stride 152 B

    const int t    = threadIdx.x;
    const int lane = t & 63;
    const int wave = t >> 6;
    const int quad = lane >> 4;
    const int l15  = lane & 15;
    const int h    = blockIdx.y;
    const int q0   = blockIdx.x * 64;
    const int cb   = h * DH;

    // Q fragments (A-operand): lane holds Q[q0+wave*16+l15][kh*32+quad*8+j]
    const int qrow = q0 + wave * 16 + l15;
    bf16x8 aQ[2];
    #pragma unroll
    for (int kh = 0; kh < 2; ++kh)
        aQ[kh] = *(const bf16x8*)(Q + (long)qrow * DM + cb + kh * 32 + quad * 8);

    // ones-column B fragment: B[n=0][k]=1 else 0 -> row sums into col 0
    bf16 oneb = f2bf(l15 == 0 ? 1.0f : 0.0f);
    bf16x8 bOnes;
    #pragma unroll
    for (int j = 0; j < 8; ++j) bOnes[j] = oneb;

    f32x4 o_acc[4], l_acc;
    #pragma unroll
    for (int dt = 0; dt < 4; ++dt) o_acc[dt] = f32x4{0.f, 0.f, 0.f, 0.f};
    l_acc = f32x4{0.f, 0.f, 0.f, 0.f};

    const float SCL = 0.18033688f;   // 0.125 * log2(e)

    for (int kv0 = 0; kv0 < SEQ; kv0 += 64) {
        __syncthreads();   // prior tile's Kb/Vt reads complete
        #pragma unroll
        for (int s = 0; s < 2; ++s) {
            int idx = t + s * 256;        // 0..511
            int key = idx >> 3;           // 0..63
            int dg  = idx & 7;
            *(uint4*)&Kb[key][dg * 8] =
                *(const uint4*)(Kg + (long)(kv0 + key) * DM + cb + dg * 8);
            bf16x8 vv = *(const bf16x8*)(Vg + (long)(kv0 + key) * DM + cb + dg * 8);
            int swz = key ^ (dg * 8);
            #pragma unroll
            for (int j = 0; j < 8; ++j) Vt[dg * 8 + j][swz] = vv[j];
        }
        __syncthreads();

        // ---- QK^T: S[row=quad*4+r][key=kt*16+l15] ----
        f32x4 s4[4];
        #pragma unroll
        for (int kt = 0; kt < 4; ++kt) {
            bf16x8 b0 = *(const bf16x8*)&Kb[kt * 16 + l15][quad * 8];
            bf16x8 b1 = *(const bf16x8*)&Kb[kt * 16 + l15][32 + quad * 8];
            f32x4 s = f32x4{0.f, 0.f, 0.f, 0.f};
            s = __builtin_amdgcn_mfma_f32_16x16x32_bf16(aQ[0], b0, s, 0, 0, 0);
            s = __builtin_amdgcn_mfma_f32_16x16x32_bf16(aQ[1], b1, s, 0, 0, 0);
            s4[kt] = s;
        }

        // ---- p = exp2(s * 0.125*log2e), round to bf16, per-wave LDS ----
        #pragma unroll
        for (int kt = 0; kt < 4; ++kt) {
            #pragma unroll
            for (int r = 0; r < 4; ++r) {
                float pv = exp2f(s4[kt][r] * SCL);
                unsigned u = __float_as_uint(pv) + 0x8000u;   // round-half-up
                Pw[wave][quad * 4 + r][kt * 16 + l15] =
                    __builtin_bit_cast(bf16, (unsigned short)(u >> 16));
            }
        }
        // same-wave LDS read-after-write: lgkmcnt handled by compiler
        bf16x8 aP[2];
        aP[0] = *(const bf16x8*)&Pw[wave][l15][quad * 8];
        aP[1] = *(const bf16x8*)&Pw[wave][l15][32 + quad * 8];

        // ---- row sums l += P . 1 ----
        l_acc = __builtin_amdgcn_mfma_f32_16x16x32_bf16(aP[0], bOnes, l_acc, 0, 0, 0);
        l_acc = __builtin_amdgcn_mfma_f32_16x16x32_bf16(aP[1], bOnes, l_acc, 0, 0, 0);

        // ---- O += P @ V ----
        #pragma unroll
        for (int dt = 0; dt < 4; ++dt) {
            int d   = dt * 16 + l15;
            int dgr = d >> 3;
            bf16x8 v0 = *(const bf16x8*)&Vt[d][((quad) ^ dgr) * 8];
            bf16x8 v1 = *(const bf16x8*)&Vt[d][((4 + quad) ^ dgr) * 8];
            o_acc[dt] = __builtin_amdgcn_mfma_f32_16x16x32_bf16(aP[0], v0, o_acc[dt], 0, 0, 0);
            o_acc[dt] = __builtin_amdgcn_mfma_f32_16x16x32_bf16(aP[1], v1, o_acc[dt], 0, 0, 0);
        }
    }

    // normalize: l for row quad*4+r lives in lane quad*16 (col 0)
    #pragma unroll
    for (int r = 0; r < 4; ++r) {
        float l   = __shfl(l_acc[r], lane & 48);
        float inv = 1.f / l;
        int row   = q0 + wave * 16 + quad * 4 + r;
        #pragma unroll
        for (int dt = 0; dt < 4; ++dt)
            O[(long)row * DM + cb + dt * 16 + l15] = f2bf(o_acc[dt][r] * inv);
    }
}

// ---------------------------------------------------------------------------
// LayerNorm over last dim (1024), one block/row. In-place safe.
// ---------------------------------------------------------------------------
__global__ __launch_bounds__(256) void ln_k(
    const float* __restrict__ X, const float* __restrict__ g,
    const float* __restrict__ b, float* __restrict__ out,
    bf16* __restrict__ out16)
{
    const int row = blockIdx.x;
    const int t   = threadIdx.x;
    const float* xr = X + (long)row * DM;

    float4 v = *(const float4*)(xr + (t << 2));
    float s1 = v.x + v.y + v.z + v.w;
    float s2 = v.x * v.x + v.y * v.y + v.z * v.z + v.w * v.w;
    #pragma unroll
    for (int off = 32; off > 0; off >>= 1) {
        s1 += __shfl_xor(s1, off);
        s2 += __shfl_xor(s2, off);
    }
    __shared__ float red[8];
    int wid = t >> 6, lid = t & 63;
    if (lid == 0) { red[wid] = s1; red[4 + wid] = s2; }
    __syncthreads();
    s1 = red[0] + red[1] + red[2] + red[3];
    s2 = red[4] + red[5] + red[6] + red[7];

    float mu   = s1 * (1.f / DM);
    float var  = s2 * (1.f / DM) - mu * mu;
    float rstd = rsqrtf(var + 1e-5f);

    float4 gv = *(const float4*)(g + (t << 2));
    float4 bv = *(const float4*)(b + (t << 2));
    float4 ov;
    ov.x = (v.x - mu) * rstd * gv.x + bv.x;
    ov.y = (v.y - mu) * rstd * gv.y + bv.y;
    ov.z = (v.z - mu) * rstd * gv.z + bv.z;
    ov.w = (v.w - mu) * rstd * gv.w + bv.w;
    *(float4*)(out + (long)row * DM + (t << 2)) = ov;
    if (out16) {
        ushort4 o;
        o.x = f2bfu(ov.x); o.y = f2bfu(ov.y); o.z = f2bfu(ov.z); o.w = f2bfu(ov.w);
        *(ushort4*)((unsigned short*)out16 + (long)row * DM + (t << 2)) = o;
    }
}

// ---------------------------------------------------------------------------
extern "C" void kernel_launch(void* const* d_in, const int* in_sizes, int n_in,
                              void* d_out, int out_size, void* d_ws, size_t ws_size,
                              hipStream_t stream)
{
    const float* x       = (const float*)d_in[0];
    const float* q_in_w  = (const float*)d_in[1];
    const float* q_in_b  = (const float*)d_in[2];
    const float* k_in_w  = (const float*)d_in[3];
    const float* k_in_b  = (const float*)d_in[4];
    const float* v_in_w  = (const float*)d_in[5];
    const float* v_in_b  = (const float*)d_in[6];
    const float* out_w   = (const float*)d_in[7];
    const float* out_b   = (const float*)d_in[8];
    const float* ffn1_w  = (const float*)d_in[9];
    const float* ffn1_b  = (const float*)d_in[10];
    const float* ffn2_w  = (const float*)d_in[11];
    const float* ffn2_b  = (const float*)d_in[12];
    const float* n1_g    = (const float*)d_in[13];
    const float* n1_b    = (const float*)d_in[14];
    const float* n2_g    = (const float*)d_in[15];
    const float* n2_b    = (const float*)d_in[16];
    const float* q_out_w = (const float*)d_in[17];
    const float* q_out_b = (const float*)d_in[18];
    const float* k_out_w = (const float*)d_in[19];
    const float* k_out_b = (const float*)d_in[20];
    const float* v_out_w = (const float*)d_in[21];
    const float* v_out_b = (const float*)d_in[22];

    float* out = (float*)d_out;
    const long SD = (long)SEQ * DM;           // 2 M elements
    const long MB = 1024 * 1024;

    // --- workspace layout: 48 MiB (proven safe in round 3) ---
    char* w = (char*)d_ws;
    bf16* xbf   = (bf16*)(w);
    bf16* qb    = (bf16*)(w + 4  * MB);
    bf16* kb    = (bf16*)(w + 8  * MB);
    bf16* vb    = (bf16*)(w + 12 * MB);
    bf16* atnb  = (bf16*)(w + 16 * MB);
    bf16* f1    = (bf16*)(w + 4  * MB);       // overlays qb..atnb (dead)
    float* tmp  = (float*)(w + 20 * MB);      // pre-LN1, then h32 in-place
    bf16* h16   = (bf16*)(w + 28 * MB);
    bf16* wqi   = (bf16*)(w + 32 * MB);
    bf16* wki   = (bf16*)(w + 34 * MB);
    bf16* wvi   = (bf16*)(w + 36 * MB);
    bf16* wo    = (bf16*)(w + 38 * MB);
    bf16* wf2   = (bf16*)(w + 32 * MB);       // overlays wqi..wo (dead)
    bf16* wf1   = (bf16*)(w + 40 * MB);
    bf16* wqo   = (bf16*)(w + 40 * MB);       // overlays wf1 (dead)
    bf16* wko   = (bf16*)(w + 42 * MB);
    bf16* wvo   = (bf16*)(w + 44 * MB);
    bf16* ybf   = (bf16*)(w);                 // overlays xbf (dead)
    float* y32  = out + 3 * SD;               // pre-LN2 in d_out, LN2 in-place

    dim3 blk(256);
    const int DD = DM * DM;
    auto conv = [&](const float* s, bf16* d, int n) {
        conv_k<<<dim3(n / 1024), blk, 0, stream>>>(s, d, n);
    };

    // --- initial fp32 -> bf16 conversions ---
    conv(x, xbf, (int)SD);
    conv(q_in_w, wqi, DD);  conv(k_in_w, wki, DD);  conv(v_in_w, wvi, DD);
    conv(out_w, wo, DD);
    conv(ffn1_w, wf1, DM * DFF);

    // --- q/k/v in-projections (z-batched, 128x128 tiles, 384 blocks) ---
    {
        GemmPtrs p{};
        p.W[0] = wqi; p.W[1] = wki; p.W[2] = wvi;
        p.bias[0] = q_in_b; p.bias[1] = k_in_b; p.bias[2] = v_in_b;
        p.out16[0] = qb; p.out16[1] = kb; p.out16[2] = vb;
        gemm_bf16_k<128, 128><<<dim3(DM / 128, SEQ / 128, 3), blk, 0, stream>>>(
            xbf, nullptr, p, DM, DM, 0);
    }

    // --- attention (512 blocks) ---
    attn_mfma_k<<<dim3(SEQ / 64, NH), blk, 0, stream>>>(qb, kb, vb, atnb);

    // --- out-projection + residual(x) -> tmp (64x128 tiles, 256 blocks) ---
    {
        GemmPtrs p{};
        p.W[0] = wo; p.bias[0] = out_b; p.out32[0] = tmp;
        gemm_bf16_k<64, 128><<<dim3(DM / 128, SEQ / 64, 1), blk, 0, stream>>>(
            atnb, x, p, DM, DM, 0);
    }
    conv(ffn2_w, wf2, DM * DFF);   // wqi..wo dead now

    ln_k<<<SEQ, blk, 0, stream>>>(tmp, n1_g, n1_b, tmp, h16);   // in-place

    // --- FFN1 (128x128, 512 blocks, relu) ---
    {
        GemmPtrs p{};
        p.W[0] = wf1; p.bias[0] = ffn1_b; p.out16[0] = f1;
        gemm_bf16_k<128, 128><<<dim3(DFF / 128, SEQ / 128, 1), blk, 0, stream>>>(
            h16, nullptr, p, DFF, DM, 1);
    }
    conv(q_out_w, wqo, DD); conv(k_out_w, wko, DD); conv(v_out_w, wvo, DD);

    // --- FFN2 + residual(h) -> y32 (64x128, 256 blocks) ---
    {
        GemmPtrs p{};
        p.W[0] = wf2; p.bias[0] = ffn2_b; p.out32[0] = y32;
        gemm_bf16_k<64, 128><<<dim3(DM / 128, SEQ / 64, 1), blk, 0, stream>>>(
            f1, tmp, p, DM, DFF, 0);
    }
    ln_k<<<SEQ, blk, 0, stream>>>(y32, n2_g, n2_b, y32, ybf);   // in-place

    // --- next-layer projections (z-batched, 128x128, 384 blocks) ---
    {
        GemmPtrs p{};
        p.W[0] = wqo; p.W[1] = wko; p.W[2] = wvo;
        p.bias[0] = q_out_b; p.bias[1] = k_out_b; p.bias[2] = v_out_b;
        p.out32[0] = out; p.out32[1] = out + SD; p.out32[2] = out + 2 * SD;
        gemm_bf16_k<128, 128><<<dim3(DM / 128, SEQ / 128, 3), blk, 0, stream>>>(
            ybf, nullptr, p, DM, DM, 0);
    }
}

// Round 5
// 370.832 us; speedup vs baseline: 3.8587x; 1.2094x over previous
//
#include <hip/hip_runtime.h>
#include <math.h>

#define SEQ   2048
#define DM    1024
#define NH    16
#define DH    64
#define DFF   4096
#define KVSPLIT 4

typedef __bf16 bf16;
using bf16x8 = __attribute__((ext_vector_type(8))) __bf16;
using f32x4  = __attribute__((ext_vector_type(4))) float;

__device__ __forceinline__ unsigned short f2bfu(float f) {
    unsigned int u = __float_as_uint(f);
    u += 0x7FFF + ((u >> 16) & 1);          // round-to-nearest-even
    return (unsigned short)(u >> 16);
}
__device__ __forceinline__ bf16 f2bf(float f) {
    unsigned short s = f2bfu(f);
    return __builtin_bit_cast(bf16, s);
}

// async global->LDS, 16B per lane. lds base must be wave-uniform; HW adds lane*16.
__device__ __forceinline__ void gll16(const bf16* g, bf16* lds_base) {
    __builtin_amdgcn_global_load_lds(
        (const __attribute__((address_space(1))) unsigned int*)g,
        (__attribute__((address_space(3))) unsigned int*)lds_base, 16, 0, 0);
}

// ---------------------------------------------------------------------------
// fp32 -> bf16 conversions: single-tensor and 6-way segmented (blockIdx.y)
// ---------------------------------------------------------------------------
__global__ __launch_bounds__(256) void conv_k(const float* __restrict__ src,
                                              bf16* __restrict__ dst, int n) {
    int i = (blockIdx.x * 256 + threadIdx.x) * 4;
    if (i >= n) return;
    float4 v = *(const float4*)(src + i);
    ushort4 o;
    o.x = f2bfu(v.x); o.y = f2bfu(v.y); o.z = f2bfu(v.z); o.w = f2bfu(v.w);
    *(ushort4*)((unsigned short*)dst + i) = o;
}

struct ConvSeg  { const float* src; bf16* dst; int n; };
struct ConvSegs { ConvSeg s[6]; };

__global__ __launch_bounds__(256) void conv_multi_k(ConvSegs cs) {
    ConvSeg sg = cs.s[blockIdx.y];
    int i = (blockIdx.x * 256 + threadIdx.x) * 4;
    if (i >= sg.n) return;
    float4 v = *(const float4*)(sg.src + i);
    ushort4 o;
    o.x = f2bfu(v.x); o.y = f2bfu(v.y); o.z = f2bfu(v.z); o.w = f2bfu(v.w);
    *(ushort4*)((unsigned short*)sg.dst + i) = o;
}

// ---------------------------------------------------------------------------
// bf16 MFMA GEMM: C[M,N] = A[M,K] @ W[N,K]^T + bias (+res fp32) (+relu)
// Block tile BM x BN, 256 threads = 4 waves (2x2). BK=32.
// ---------------------------------------------------------------------------
struct GemmPtrs {
    const bf16* W[3];
    const float* bias[3];
    float* out32[3];
    bf16*  out16[3];
};

template<int BM, int BN>
__global__ __launch_bounds__(256) void gemm_bf16_k(
    const bf16* __restrict__ A, const float* __restrict__ res,
    GemmPtrs p, int N, int K, int relu)
{
    constexpr int TM = BM / 32;
    constexpr int TN = BN / 32;
    __shared__ bf16 As[BM][32];
    __shared__ bf16 Ws[BN][32];

    const int t    = threadIdx.x;
    const int lane = t & 63;
    const int wave = t >> 6;
    const int quad = lane >> 4;
    const int l15  = lane & 15;
    const int wm   = (wave >> 1) * (BM / 2);
    const int wn   = (wave & 1) * (BN / 2);
    const int m0   = blockIdx.y * BM;
    const int n0   = blockIdx.x * BN;
    const bf16* __restrict__ W = p.W[blockIdx.z];

    f32x4 acc[TM][TN];
    #pragma unroll
    for (int i = 0; i < TM; ++i)
        #pragma unroll
        for (int j = 0; j < TN; ++j)
            acc[i][j] = f32x4{0.f, 0.f, 0.f, 0.f};

    for (int k0 = 0; k0 < K; k0 += 32) {
        #pragma unroll
        for (int s = 0; s < BM / 64; ++s) {
            int base = s * 256 + wave * 64;
            int idx  = base + lane;
            gll16(A + (long)(m0 + (idx >> 2)) * K + k0 + (idx & 3) * 8,
                  &As[0][0] + (long)base * 8);
        }
        #pragma unroll
        for (int s = 0; s < BN / 64; ++s) {
            int base = s * 256 + wave * 64;
            int idx  = base + lane;
            gll16(W + (long)(n0 + (idx >> 2)) * K + k0 + (idx & 3) * 8,
                  &Ws[0][0] + (long)base * 8);
        }
        __syncthreads();

        bf16x8 a[TM], b[TN];
        #pragma unroll
        for (int i = 0; i < TM; ++i)
            a[i] = *(const bf16x8*)&As[wm + i * 16 + l15][quad * 8];
        #pragma unroll
        for (int j = 0; j < TN; ++j)
            b[j] = *(const bf16x8*)&Ws[wn + j * 16 + l15][quad * 8];
        #pragma unroll
        for (int i = 0; i < TM; ++i)
            #pragma unroll
            for (int j = 0; j < TN; ++j)
                acc[i][j] = __builtin_amdgcn_mfma_f32_16x16x32_bf16(
                    a[i], b[j], acc[i][j], 0, 0, 0);
        __syncthreads();
    }

    float* o32 = p.out32[blockIdx.z];
    bf16*  o16 = p.out16[blockIdx.z];
    const float* bias = p.bias[blockIdx.z];
    #pragma unroll
    for (int j = 0; j < TN; ++j) {
        int n = n0 + wn + j * 16 + l15;
        float bv = bias[n];
        #pragma unroll
        for (int i = 0; i < TM; ++i) {
            #pragma unroll
            for (int r = 0; r < 4; ++r) {
                int m = m0 + wm + i * 16 + quad * 4 + r;
                float v = acc[i][j][r] + bv;
                if (res)  v += res[(long)m * N + n];
                if (relu) v = fmaxf(v, 0.f);
                if (o32) o32[(long)m * N + n] = v;
                if (o16) o16[(long)m * N + n] = f2bf(v);
            }
        }
    }
}

// ---------------------------------------------------------------------------
// Flash attention, bf16 MFMA, fixed-max softmax, kv-split across blocks.
// Block = 1 head x 64 q rows x 1 kv-quarter (512 keys). Grid 32x16x4 = 2048.
// Writes UNNORMALIZED partial O (bf16) + partial l (fp32); additive combine.
// ---------------------------------------------------------------------------
__global__ __launch_bounds__(256) void attn_mfma_k(
    const bf16* __restrict__ Q, const bf16* __restrict__ Kg,
    const bf16* __restrict__ Vg, bf16* __restrict__ Opart,
    float* __restrict__ lpart)
{
    __shared__ bf16 Kb[64][72];      // [key][d], stride 144 B
    __shared__ bf16 Vt[64][72];      // [d][key^swz]
    __shared__ bf16 Pw[4][16][76];   // per-wave P

    const int t    = threadIdx.x;
    const int lane = t & 63;
    const int wave = t >> 6;
    const int quad = lane >> 4;
    const int l15  = lane & 15;
    const int h    = blockIdx.y;
    const int q0   = blockIdx.x * 64;
    const int spl  = blockIdx.z;
    const int cb   = h * DH;
    const long SD  = (long)SEQ * DM;

    const int qrow = q0 + wave * 16 + l15;
    bf16x8 aQ[2];
    #pragma unroll
    for (int kh = 0; kh < 2; ++kh)
        aQ[kh] = *(const bf16x8*)(Q + (long)qrow * DM + cb + kh * 32 + quad * 8);

    bf16 oneb = f2bf(l15 == 0 ? 1.0f : 0.0f);
    bf16x8 bOnes;
    #pragma unroll
    for (int j = 0; j < 8; ++j) bOnes[j] = oneb;

    f32x4 o_acc[4], l_acc;
    #pragma unroll
    for (int dt = 0; dt < 4; ++dt) o_acc[dt] = f32x4{0.f, 0.f, 0.f, 0.f};
    l_acc = f32x4{0.f, 0.f, 0.f, 0.f};

    const float SCL = 0.18033688f;   // 0.125 * log2(e)
    const int kv_lo = spl * (SEQ / KVSPLIT);
    const int kv_hi = kv_lo + SEQ / KVSPLIT;

    for (int kv0 = kv_lo; kv0 < kv_hi; kv0 += 64) {
        __syncthreads();
        #pragma unroll
        for (int s = 0; s < 2; ++s) {
            int idx = t + s * 256;
            int key = idx >> 3;
            int dg  = idx & 7;
            *(uint4*)&Kb[key][dg * 8] =
                *(const uint4*)(Kg + (long)(kv0 + key) * DM + cb + dg * 8);
            bf16x8 vv = *(const bf16x8*)(Vg + (long)(kv0 + key) * DM + cb + dg * 8);
            int swz = key ^ (dg * 8);
            #pragma unroll
            for (int j = 0; j < 8; ++j) Vt[dg * 8 + j][swz] = vv[j];
        }
        __syncthreads();

        f32x4 s4[4];
        #pragma unroll
        for (int kt = 0; kt < 4; ++kt) {
            bf16x8 b0 = *(const bf16x8*)&Kb[kt * 16 + l15][quad * 8];
            bf16x8 b1 = *(const bf16x8*)&Kb[kt * 16 + l15][32 + quad * 8];
            f32x4 s = f32x4{0.f, 0.f, 0.f, 0.f};
            s = __builtin_amdgcn_mfma_f32_16x16x32_bf16(aQ[0], b0, s, 0, 0, 0);
            s = __builtin_amdgcn_mfma_f32_16x16x32_bf16(aQ[1], b1, s, 0, 0, 0);
            s4[kt] = s;
        }

        #pragma unroll
        for (int kt = 0; kt < 4; ++kt) {
            #pragma unroll
            for (int r = 0; r < 4; ++r) {
                float pv = exp2f(s4[kt][r] * SCL);
                unsigned u = __float_as_uint(pv) + 0x8000u;
                Pw[wave][quad * 4 + r][kt * 16 + l15] =
                    __builtin_bit_cast(bf16, (unsigned short)(u >> 16));
            }
        }
        bf16x8 aP[2];
        aP[0] = *(const bf16x8*)&Pw[wave][l15][quad * 8];
        aP[1] = *(const bf16x8*)&Pw[wave][l15][32 + quad * 8];

        l_acc = __builtin_amdgcn_mfma_f32_16x16x32_bf16(aP[0], bOnes, l_acc, 0, 0, 0);
        l_acc = __builtin_amdgcn_mfma_f32_16x16x32_bf16(aP[1], bOnes, l_acc, 0, 0, 0);

        #pragma unroll
        for (int dt = 0; dt < 4; ++dt) {
            int d   = dt * 16 + l15;
            int dgr = d >> 3;
            bf16x8 v0 = *(const bf16x8*)&Vt[d][((quad) ^ dgr) * 8];
            bf16x8 v1 = *(const bf16x8*)&Vt[d][((4 + quad) ^ dgr) * 8];
            o_acc[dt] = __builtin_amdgcn_mfma_f32_16x16x32_bf16(aP[0], v0, o_acc[dt], 0, 0, 0);
            o_acc[dt] = __builtin_amdgcn_mfma_f32_16x16x32_bf16(aP[1], v1, o_acc[dt], 0, 0, 0);
        }
    }

    // store unnormalized partials
    #pragma unroll
    for (int r = 0; r < 4; ++r) {
        int row = q0 + wave * 16 + quad * 4 + r;
        #pragma unroll
        for (int dt = 0; dt < 4; ++dt)
            Opart[(long)spl * SD + (long)row * DM + cb + dt * 16 + l15] =
                f2bf(o_acc[dt][r]);
        if (l15 == 0)
            lpart[((long)spl * NH + h) * SEQ + row] = l_acc[r];
    }
}

// ---------------------------------------------------------------------------
// Combine kv-split partials: O = (sum_k Opart) / (sum_k l) -> bf16
// ---------------------------------------------------------------------------
__global__ __launch_bounds__(256) void attn_reduce_k(
    const bf16* __restrict__ Opart, const float* __restrict__ lpart,
    bf16* __restrict__ O)
{
    const long SD = (long)SEQ * DM;
    long i = ((long)blockIdx.x * 256 + threadIdx.x) * 8;
    int row = (int)(i / DM);
    int h   = (int)((i % DM) / DH);

    float l = 0.f;
    #pragma unroll
    for (int k = 0; k < KVSPLIT; ++k)
        l += lpart[((long)k * NH + h) * SEQ + row];
    float inv = 1.f / l;

    float acc[8] = {};
    #pragma unroll
    for (int k = 0; k < KVSPLIT; ++k) {
        bf16x8 v = *(const bf16x8*)(Opart + (long)k * SD + i);
        #pragma unroll
        for (int j = 0; j < 8; ++j) acc[j] += (float)v[j];
    }
    bf16x8 o;
    #pragma unroll
    for (int j = 0; j < 8; ++j) o[j] = f2bf(acc[j] * inv);
    *(bf16x8*)(O + i) = o;
}

// ---------------------------------------------------------------------------
// LayerNorm over last dim (1024), one block/row. In-place safe.
// ---------------------------------------------------------------------------
__global__ __launch_bounds__(256) void ln_k(
    const float* __restrict__ X, const float* __restrict__ g,
    const float* __restrict__ b, float* __restrict__ out,
    bf16* __restrict__ out16)
{
    const int row = blockIdx.x;
    const int t   = threadIdx.x;
    const float* xr = X + (long)row * DM;

    float4 v = *(const float4*)(xr + (t << 2));
    float s1 = v.x + v.y + v.z + v.w;
    float s2 = v.x * v.x + v.y * v.y + v.z * v.z + v.w * v.w;
    #pragma unroll
    for (int off = 32; off > 0; off >>= 1) {
        s1 += __shfl_xor(s1, off);
        s2 += __shfl_xor(s2, off);
    }
    __shared__ float red[8];
    int wid = t >> 6, lid = t & 63;
    if (lid == 0) { red[wid] = s1; red[4 + wid] = s2; }
    __syncthreads();
    s1 = red[0] + red[1] + red[2] + red[3];
    s2 = red[4] + red[5] + red[6] + red[7];

    float mu   = s1 * (1.f / DM);
    float var  = s2 * (1.f / DM) - mu * mu;
    float rstd = rsqrtf(var + 1e-5f);

    float4 gv = *(const float4*)(g + (t << 2));
    float4 bv = *(const float4*)(b + (t << 2));
    float4 ov;
    ov.x = (v.x - mu) * rstd * gv.x + bv.x;
    ov.y = (v.y - mu) * rstd * gv.y + bv.y;
    ov.z = (v.z - mu) * rstd * gv.z + bv.z;
    ov.w = (v.w - mu) * rstd * gv.w + bv.w;
    *(float4*)(out + (long)row * DM + (t << 2)) = ov;
    if (out16) {
        ushort4 o;
        o.x = f2bfu(ov.x); o.y = f2bfu(ov.y); o.z = f2bfu(ov.z); o.w = f2bfu(ov.w);
        *(ushort4*)((unsigned short*)out16 + (long)row * DM + (t << 2)) = o;
    }
}

// ---------------------------------------------------------------------------
extern "C" void kernel_launch(void* const* d_in, const int* in_sizes, int n_in,
                              void* d_out, int out_size, void* d_ws, size_t ws_size,
                              hipStream_t stream)
{
    const float* x       = (const float*)d_in[0];
    const float* q_in_w  = (const float*)d_in[1];
    const float* q_in_b  = (const float*)d_in[2];
    const float* k_in_w  = (const float*)d_in[3];
    const float* k_in_b  = (const float*)d_in[4];
    const float* v_in_w  = (const float*)d_in[5];
    const float* v_in_b  = (const float*)d_in[6];
    const float* out_w   = (const float*)d_in[7];
    const float* out_b   = (const float*)d_in[8];
    const float* ffn1_w  = (const float*)d_in[9];
    const float* ffn1_b  = (const float*)d_in[10];
    const float* ffn2_w  = (const float*)d_in[11];
    const float* ffn2_b  = (const float*)d_in[12];
    const float* n1_g    = (const float*)d_in[13];
    const float* n1_b    = (const float*)d_in[14];
    const float* n2_g    = (const float*)d_in[15];
    const float* n2_b    = (const float*)d_in[16];
    const float* q_out_w = (const float*)d_in[17];
    const float* q_out_b = (const float*)d_in[18];
    const float* k_out_w = (const float*)d_in[19];
    const float* k_out_b = (const float*)d_in[20];
    const float* v_out_w = (const float*)d_in[21];
    const float* v_out_b = (const float*)d_in[22];

    float* out = (float*)d_out;
    const long SD = (long)SEQ * DM;
    const long MB = 1024 * 1024;

    // --- workspace layout: 48 MiB (proven safe) ---
    // [0,4)    xbf (dead after in-proj), later ybf
    // [4,16)   qb/kb/vb          } later f1 [4,20)
    // [16,20)  atnb              }
    // [20,36)  Opart (4x4MB, live only attn..reduce); later tmp [20,28) + h16 [28,32)
    // [36,36.5) lpart            (inside dead wvi region)
    // [32,38)  wqi/wki/wvi (dead after in-proj; Opart/lpart overlay, then wf2)
    // [38,40)  wo (dead after out-proj)
    // [32,40)  wf2 (after out-proj)
    // [40,48)  wf1, later wqo/wko/wvo (after FFN1)
    char* w = (char*)d_ws;
    bf16* xbf    = (bf16*)(w);
    bf16* qb     = (bf16*)(w + 4  * MB);
    bf16* kb     = (bf16*)(w + 8  * MB);
    bf16* vb     = (bf16*)(w + 12 * MB);
    bf16* atnb   = (bf16*)(w + 16 * MB);
    bf16* f1     = (bf16*)(w + 4  * MB);
    bf16* Opart  = (bf16*)(w + 20 * MB);      // 16 MB, attn..reduce only
    float* lpart = (float*)(w + 36 * MB);     // 512 KB, attn..reduce only
    float* tmp   = (float*)(w + 20 * MB);     // pre-LN1, then h32 in-place
    bf16* h16    = (bf16*)(w + 28 * MB);
    bf16* wqi    = (bf16*)(w + 32 * MB);
    bf16* wki    = (bf16*)(w + 34 * MB);
    bf16* wvi    = (bf16*)(w + 36 * MB);
    bf16* wo     = (bf16*)(w + 38 * MB);
    bf16* wf2    = (bf16*)(w + 32 * MB);      // after out-proj
    bf16* wf1    = (bf16*)(w + 40 * MB);
    bf16* wqo    = (bf16*)(w + 40 * MB);      // after FFN1
    bf16* wko    = (bf16*)(w + 42 * MB);
    bf16* wvo    = (bf16*)(w + 44 * MB);
    bf16* ybf    = (bf16*)(w);
    float* y32   = out + 3 * SD;

    dim3 blk(256);
    const int DD = DM * DM;

    // --- group-1 conversions (x + 5 weight tensors), one launch ---
    {
        ConvSegs cs;
        cs.s[0] = {x,      xbf, (int)SD};
        cs.s[1] = {q_in_w, wqi, DD};
        cs.s[2] = {k_in_w, wki, DD};
        cs.s[3] = {v_in_w, wvi, DD};
        cs.s[4] = {out_w,  wo,  DD};
        cs.s[5] = {ffn1_w, wf1, DM * DFF};
        conv_multi_k<<<dim3(DM * DFF / 1024, 6), blk, 0, stream>>>(cs);
    }

    // --- q/k/v in-projections (128x64 tiles, 768 blocks) ---
    {
        GemmPtrs p{};
        p.W[0] = wqi; p.W[1] = wki; p.W[2] = wvi;
        p.bias[0] = q_in_b; p.bias[1] = k_in_b; p.bias[2] = v_in_b;
        p.out16[0] = qb; p.out16[1] = kb; p.out16[2] = vb;
        gemm_bf16_k<128, 64><<<dim3(DM / 64, SEQ / 128, 3), blk, 0, stream>>>(
            xbf, nullptr, p, DM, DM, 0);
    }

    // --- attention: kv-split x4 (2048 blocks) + reduce ---
    attn_mfma_k<<<dim3(SEQ / 64, NH, KVSPLIT), blk, 0, stream>>>(
        qb, kb, vb, Opart, lpart);
    attn_reduce_k<<<dim3((int)(SD / 2048)), blk, 0, stream>>>(Opart, lpart, atnb);

    // --- out-projection + residual(x) -> tmp (64x64 tiles, 512 blocks) ---
    {
        GemmPtrs p{};
        p.W[0] = wo; p.bias[0] = out_b; p.out32[0] = tmp;
        gemm_bf16_k<64, 64><<<dim3(DM / 64, SEQ / 64, 1), blk, 0, stream>>>(
            atnb, x, p, DM, DM, 0);
    }
    conv_k<<<dim3(DM * DFF / 1024), blk, 0, stream>>>(ffn2_w, wf2, DM * DFF);

    ln_k<<<SEQ, blk, 0, stream>>>(tmp, n1_g, n1_b, tmp, h16);   // in-place

    // --- FFN1 (128x64, 1024 blocks, relu) ---
    {
        GemmPtrs p{};
        p.W[0] = wf1; p.bias[0] = ffn1_b; p.out16[0] = f1;
        gemm_bf16_k<128, 64><<<dim3(DFF / 64, SEQ / 128, 1), blk, 0, stream>>>(
            h16, nullptr, p, DFF, DM, 1);
    }
    // --- group-3 conversions (next-layer weights) ---
    {
        ConvSegs cs;
        cs.s[0] = {q_out_w, wqo, DD};
        cs.s[1] = {k_out_w, wko, DD};
        cs.s[2] = {v_out_w, wvo, DD};
        cs.s[3] = cs.s[0]; cs.s[4] = cs.s[0]; cs.s[5] = cs.s[0];
        conv_multi_k<<<dim3(DD / 1024, 3), blk, 0, stream>>>(cs);
    }

    // --- FFN2 + residual(h) -> y32 (64x64, 512 blocks) ---
    {
        GemmPtrs p{};
        p.W[0] = wf2; p.bias[0] = ffn2_b; p.out32[0] = y32;
        gemm_bf16_k<64, 64><<<dim3(DM / 64, SEQ / 64, 1), blk, 0, stream>>>(
            f1, tmp, p, DM, DFF, 0);
    }
    ln_k<<<SEQ, blk, 0, stream>>>(y32, n2_g, n2_b, y32, ybf);   // in-place

    // --- next-layer projections (128x64, 768 blocks) ---
    {
        GemmPtrs p{};
        p.W[0] = wqo; p.W[1] = wko; p.W[2] = wvo;
        p.bias[0] = q_out_b; p.bias[1] = k_out_b; p.bias[2] = v_out_b;
        p.out32[0] = out; p.out32[1] = out + SD; p.out32[2] = out + 2 * SD;
        gemm_bf16_k<128, 64><<<dim3(DM / 64, SEQ / 128, 3), blk, 0, stream>>>(
            ybf, nullptr, p, DM, DM, 0);
    }
}

// Round 6
// 355.616 us; speedup vs baseline: 4.0238x; 1.0428x over previous
//
#include <hip/hip_runtime.h>
#include <math.h>

#define SEQ   2048
#define DM    1024
#define NH    16
#define DH    64
#define DFF   4096
#define KVSPLIT 4

typedef __bf16 bf16;
using bf16x8 = __attribute__((ext_vector_type(8))) __bf16;
using f32x4  = __attribute__((ext_vector_type(4))) float;

__device__ __forceinline__ unsigned short f2bfu(float f) {
    unsigned int u = __float_as_uint(f);
    u += 0x7FFF + ((u >> 16) & 1);          // round-to-nearest-even
    return (unsigned short)(u >> 16);
}
__device__ __forceinline__ bf16 f2bf(float f) {
    unsigned short s = f2bfu(f);
    return __builtin_bit_cast(bf16, s);
}

// async global->LDS, 16B per lane. lds base must be wave-uniform; HW adds lane*16.
__device__ __forceinline__ void gll16(const bf16* g, bf16* lds_base) {
    __builtin_amdgcn_global_load_lds(
        (const __attribute__((address_space(1))) unsigned int*)g,
        (__attribute__((address_space(3))) unsigned int*)lds_base, 16, 0, 0);
}

// ---------------------------------------------------------------------------
// fp32 -> bf16 conversions: single-tensor and 6-way segmented (blockIdx.y)
// ---------------------------------------------------------------------------
__global__ __launch_bounds__(256) void conv_k(const float* __restrict__ src,
                                              bf16* __restrict__ dst, int n) {
    int i = (blockIdx.x * 256 + threadIdx.x) * 4;
    if (i >= n) return;
    float4 v = *(const float4*)(src + i);
    ushort4 o;
    o.x = f2bfu(v.x); o.y = f2bfu(v.y); o.z = f2bfu(v.z); o.w = f2bfu(v.w);
    *(ushort4*)((unsigned short*)dst + i) = o;
}

struct ConvSeg  { const float* src; bf16* dst; int n; };
struct ConvSegs { ConvSeg s[6]; };

__global__ __launch_bounds__(256) void conv_multi_k(ConvSegs cs) {
    ConvSeg sg = cs.s[blockIdx.y];
    int i = (blockIdx.x * 256 + threadIdx.x) * 4;
    if (i >= sg.n) return;
    float4 v = *(const float4*)(sg.src + i);
    ushort4 o;
    o.x = f2bfu(v.x); o.y = f2bfu(v.y); o.z = f2bfu(v.z); o.w = f2bfu(v.w);
    *(ushort4*)((unsigned short*)sg.dst + i) = o;
}

// ---------------------------------------------------------------------------
// bf16 MFMA GEMM (full-K): C = A @ W^T + bias (+relu). z batches weight sets.
// ---------------------------------------------------------------------------
struct GemmPtrs {
    const bf16* W[3];
    const float* bias[3];
    float* out32[3];
    bf16*  out16[3];
};

template<int BM, int BN>
__global__ __launch_bounds__(256) void gemm_bf16_k(
    const bf16* __restrict__ A, GemmPtrs p, int N, int K, int relu)
{
    constexpr int TM = BM / 32;
    constexpr int TN = BN / 32;
    __shared__ bf16 As[BM][32];
    __shared__ bf16 Ws[BN][32];

    const int t    = threadIdx.x;
    const int lane = t & 63;
    const int wave = t >> 6;
    const int quad = lane >> 4;
    const int l15  = lane & 15;
    const int wm   = (wave >> 1) * (BM / 2);
    const int wn   = (wave & 1) * (BN / 2);
    const int m0   = blockIdx.y * BM;
    const int n0   = blockIdx.x * BN;
    const bf16* __restrict__ W = p.W[blockIdx.z];

    f32x4 acc[TM][TN];
    #pragma unroll
    for (int i = 0; i < TM; ++i)
        #pragma unroll
        for (int j = 0; j < TN; ++j)
            acc[i][j] = f32x4{0.f, 0.f, 0.f, 0.f};

    for (int k0 = 0; k0 < K; k0 += 32) {
        #pragma unroll
        for (int s = 0; s < BM / 64; ++s) {
            int base = s * 256 + wave * 64;
            int idx  = base + lane;
            gll16(A + (long)(m0 + (idx >> 2)) * K + k0 + (idx & 3) * 8,
                  &As[0][0] + (long)base * 8);
        }
        #pragma unroll
        for (int s = 0; s < BN / 64; ++s) {
            int base = s * 256 + wave * 64;
            int idx  = base + lane;
            gll16(W + (long)(n0 + (idx >> 2)) * K + k0 + (idx & 3) * 8,
                  &Ws[0][0] + (long)base * 8);
        }
        __syncthreads();

        bf16x8 a[TM], b[TN];
        #pragma unroll
        for (int i = 0; i < TM; ++i)
            a[i] = *(const bf16x8*)&As[wm + i * 16 + l15][quad * 8];
        #pragma unroll
        for (int j = 0; j < TN; ++j)
            b[j] = *(const bf16x8*)&Ws[wn + j * 16 + l15][quad * 8];
        #pragma unroll
        for (int i = 0; i < TM; ++i)
            #pragma unroll
            for (int j = 0; j < TN; ++j)
                acc[i][j] = __builtin_amdgcn_mfma_f32_16x16x32_bf16(
                    a[i], b[j], acc[i][j], 0, 0, 0);
        __syncthreads();
    }

    float* o32 = p.out32[blockIdx.z];
    bf16*  o16 = p.out16[blockIdx.z];
    const float* bias = p.bias[blockIdx.z];
    #pragma unroll
    for (int j = 0; j < TN; ++j) {
        int n = n0 + wn + j * 16 + l15;
        float bv = bias[n];
        #pragma unroll
        for (int i = 0; i < TM; ++i) {
            #pragma unroll
            for (int r = 0; r < 4; ++r) {
                int m = m0 + wm + i * 16 + quad * 4 + r;
                float v = acc[i][j][r] + bv;
                if (relu) v = fmaxf(v, 0.f);
                if (o32) o32[(long)m * N + n] = v;
                if (o16) o16[(long)m * N + n] = f2bf(v);
            }
        }
    }
}

// ---------------------------------------------------------------------------
// Split-K GEMM: blockIdx.z owns K-slice [z*K/KS,(z+1)*K/KS); writes fp32
// partial to part + z*MN. No bias/res (applied in the fused LN reduce).
// ---------------------------------------------------------------------------
template<int BM, int BN, int KS>
__global__ __launch_bounds__(256) void gemm_splitk_k(
    const bf16* __restrict__ A, const bf16* __restrict__ W,
    float* __restrict__ part, int N, int K)
{
    constexpr int TM = BM / 32;
    constexpr int TN = BN / 32;
    __shared__ bf16 As[BM][32];
    __shared__ bf16 Ws[BN][32];

    const int t    = threadIdx.x;
    const int lane = t & 63;
    const int wave = t >> 6;
    const int quad = lane >> 4;
    const int l15  = lane & 15;
    const int wm   = (wave >> 1) * (BM / 2);
    const int wn   = (wave & 1) * (BN / 2);
    const int m0   = blockIdx.y * BM;
    const int n0   = blockIdx.x * BN;
    const int Kp   = K / KS;
    const int klo  = blockIdx.z * Kp;
    const long MN  = (long)gridDim.y * BM * N;

    f32x4 acc[TM][TN];
    #pragma unroll
    for (int i = 0; i < TM; ++i)
        #pragma unroll
        for (int j = 0; j < TN; ++j)
            acc[i][j] = f32x4{0.f, 0.f, 0.f, 0.f};

    for (int k0 = klo; k0 < klo + Kp; k0 += 32) {
        #pragma unroll
        for (int s = 0; s < BM / 64; ++s) {
            int base = s * 256 + wave * 64;
            int idx  = base + lane;
            gll16(A + (long)(m0 + (idx >> 2)) * K + k0 + (idx & 3) * 8,
                  &As[0][0] + (long)base * 8);
        }
        #pragma unroll
        for (int s = 0; s < BN / 64; ++s) {
            int base = s * 256 + wave * 64;
            int idx  = base + lane;
            gll16(W + (long)(n0 + (idx >> 2)) * K + k0 + (idx & 3) * 8,
                  &Ws[0][0] + (long)base * 8);
        }
        __syncthreads();

        bf16x8 a[TM], b[TN];
        #pragma unroll
        for (int i = 0; i < TM; ++i)
            a[i] = *(const bf16x8*)&As[wm + i * 16 + l15][quad * 8];
        #pragma unroll
        for (int j = 0; j < TN; ++j)
            b[j] = *(const bf16x8*)&Ws[wn + j * 16 + l15][quad * 8];
        #pragma unroll
        for (int i = 0; i < TM; ++i)
            #pragma unroll
            for (int j = 0; j < TN; ++j)
                acc[i][j] = __builtin_amdgcn_mfma_f32_16x16x32_bf16(
                    a[i], b[j], acc[i][j], 0, 0, 0);
        __syncthreads();
    }

    float* o = part + (long)blockIdx.z * MN;
    #pragma unroll
    for (int j = 0; j < TN; ++j) {
        int n = n0 + wn + j * 16 + l15;
        #pragma unroll
        for (int i = 0; i < TM; ++i)
            #pragma unroll
            for (int r = 0; r < 4; ++r) {
                int m = m0 + wm + i * 16 + quad * 4 + r;
                o[(long)m * N + n] = acc[i][j][r];
            }
    }
}

// ---------------------------------------------------------------------------
// Flash attention, bf16 MFMA, fixed-max softmax, kv-split across blocks.
// ---------------------------------------------------------------------------
__global__ __launch_bounds__(256) void attn_mfma_k(
    const bf16* __restrict__ Q, const bf16* __restrict__ Kg,
    const bf16* __restrict__ Vg, bf16* __restrict__ Opart,
    float* __restrict__ lpart)
{
    __shared__ bf16 Kb[64][72];
    __shared__ bf16 Vt[64][72];
    __shared__ bf16 Pw[4][16][76];

    const int t    = threadIdx.x;
    const int lane = t & 63;
    const int wave = t >> 6;
    const int quad = lane >> 4;
    const int l15  = lane & 15;
    const int h    = blockIdx.y;
    const int q0   = blockIdx.x * 64;
    const int spl  = blockIdx.z;
    const int cb   = h * DH;
    const long SD  = (long)SEQ * DM;

    const int qrow = q0 + wave * 16 + l15;
    bf16x8 aQ[2];
    #pragma unroll
    for (int kh = 0; kh < 2; ++kh)
        aQ[kh] = *(const bf16x8*)(Q + (long)qrow * DM + cb + kh * 32 + quad * 8);

    bf16 oneb = f2bf(l15 == 0 ? 1.0f : 0.0f);
    bf16x8 bOnes;
    #pragma unroll
    for (int j = 0; j < 8; ++j) bOnes[j] = oneb;

    f32x4 o_acc[4], l_acc;
    #pragma unroll
    for (int dt = 0; dt < 4; ++dt) o_acc[dt] = f32x4{0.f, 0.f, 0.f, 0.f};
    l_acc = f32x4{0.f, 0.f, 0.f, 0.f};

    const float SCL = 0.18033688f;   // 0.125 * log2(e)
    const int kv_lo = spl * (SEQ / KVSPLIT);
    const int kv_hi = kv_lo + SEQ / KVSPLIT;

    for (int kv0 = kv_lo; kv0 < kv_hi; kv0 += 64) {
        __syncthreads();
        #pragma unroll
        for (int s = 0; s < 2; ++s) {
            int idx = t + s * 256;
            int key = idx >> 3;
            int dg  = idx & 7;
            *(uint4*)&Kb[key][dg * 8] =
                *(const uint4*)(Kg + (long)(kv0 + key) * DM + cb + dg * 8);
            bf16x8 vv = *(const bf16x8*)(Vg + (long)(kv0 + key) * DM + cb + dg * 8);
            int swz = key ^ (dg * 8);
            #pragma unroll
            for (int j = 0; j < 8; ++j) Vt[dg * 8 + j][swz] = vv[j];
        }
        __syncthreads();

        f32x4 s4[4];
        #pragma unroll
        for (int kt = 0; kt < 4; ++kt) {
            bf16x8 b0 = *(const bf16x8*)&Kb[kt * 16 + l15][quad * 8];
            bf16x8 b1 = *(const bf16x8*)&Kb[kt * 16 + l15][32 + quad * 8];
            f32x4 s = f32x4{0.f, 0.f, 0.f, 0.f};
            s = __builtin_amdgcn_mfma_f32_16x16x32_bf16(aQ[0], b0, s, 0, 0, 0);
            s = __builtin_amdgcn_mfma_f32_16x16x32_bf16(aQ[1], b1, s, 0, 0, 0);
            s4[kt] = s;
        }

        #pragma unroll
        for (int kt = 0; kt < 4; ++kt) {
            #pragma unroll
            for (int r = 0; r < 4; ++r) {
                float pv = exp2f(s4[kt][r] * SCL);
                unsigned u = __float_as_uint(pv) + 0x8000u;
                Pw[wave][quad * 4 + r][kt * 16 + l15] =
                    __builtin_bit_cast(bf16, (unsigned short)(u >> 16));
            }
        }
        bf16x8 aP[2];
        aP[0] = *(const bf16x8*)&Pw[wave][l15][quad * 8];
        aP[1] = *(const bf16x8*)&Pw[wave][l15][32 + quad * 8];

        l_acc = __builtin_amdgcn_mfma_f32_16x16x32_bf16(aP[0], bOnes, l_acc, 0, 0, 0);
        l_acc = __builtin_amdgcn_mfma_f32_16x16x32_bf16(aP[1], bOnes, l_acc, 0, 0, 0);

        #pragma unroll
        for (int dt = 0; dt < 4; ++dt) {
            int d   = dt * 16 + l15;
            int dgr = d >> 3;
            bf16x8 v0 = *(const bf16x8*)&Vt[d][((quad) ^ dgr) * 8];
            bf16x8 v1 = *(const bf16x8*)&Vt[d][((4 + quad) ^ dgr) * 8];
            o_acc[dt] = __builtin_amdgcn_mfma_f32_16x16x32_bf16(aP[0], v0, o_acc[dt], 0, 0, 0);
            o_acc[dt] = __builtin_amdgcn_mfma_f32_16x16x32_bf16(aP[1], v1, o_acc[dt], 0, 0, 0);
        }
    }

    #pragma unroll
    for (int r = 0; r < 4; ++r) {
        int row = q0 + wave * 16 + quad * 4 + r;
        #pragma unroll
        for (int dt = 0; dt < 4; ++dt)
            Opart[(long)spl * SD + (long)row * DM + cb + dt * 16 + l15] =
                f2bf(o_acc[dt][r]);
        if (l15 == 0)
            lpart[((long)spl * NH + h) * SEQ + row] = l_acc[r];
    }
}

__global__ __launch_bounds__(256) void attn_reduce_k(
    const bf16* __restrict__ Opart, const float* __restrict__ lpart,
    bf16* __restrict__ O)
{
    const long SD = (long)SEQ * DM;
    long i = ((long)blockIdx.x * 256 + threadIdx.x) * 8;
    int row = (int)(i / DM);
    int h   = (int)((i % DM) / DH);

    float l = 0.f;
    #pragma unroll
    for (int k = 0; k < KVSPLIT; ++k)
        l += lpart[((long)k * NH + h) * SEQ + row];
    float inv = 1.f / l;

    float acc[8] = {};
    #pragma unroll
    for (int k = 0; k < KVSPLIT; ++k) {
        bf16x8 v = *(const bf16x8*)(Opart + (long)k * SD + i);
        #pragma unroll
        for (int j = 0; j < 8; ++j) acc[j] += (float)v[j];
    }
    bf16x8 o;
    #pragma unroll
    for (int j = 0; j < 8; ++j) o[j] = f2bf(acc[j] * inv);
    *(bf16x8*)(O + i) = o;
}

// ---------------------------------------------------------------------------
// Fused split-K reduce + bias + residual + LayerNorm. One block per row.
// x_row = sum_z part[z] + bias + res;  out = LN(x_row)*g + b
// ---------------------------------------------------------------------------
template<int NS>
__global__ __launch_bounds__(256) void ln_red_k(
    const float* __restrict__ part, const float* __restrict__ bias,
    const float* __restrict__ res, const float* __restrict__ g,
    const float* __restrict__ b, float* __restrict__ out32,
    bf16* __restrict__ out16)
{
    const long SD = (long)SEQ * DM;
    const int row = blockIdx.x;
    const int t   = threadIdx.x;
    const long off = (long)row * DM + (t << 2);

    float4 v = *(const float4*)(res + off);
    float4 bv0 = *(const float4*)(bias + (t << 2));
    v.x += bv0.x; v.y += bv0.y; v.z += bv0.z; v.w += bv0.w;
    #pragma unroll
    for (int z = 0; z < NS; ++z) {
        float4 pz = *(const float4*)(part + z * SD + off);
        v.x += pz.x; v.y += pz.y; v.z += pz.z; v.w += pz.w;
    }

    float s1 = v.x + v.y + v.z + v.w;
    float s2 = v.x * v.x + v.y * v.y + v.z * v.z + v.w * v.w;
    #pragma unroll
    for (int off2 = 32; off2 > 0; off2 >>= 1) {
        s1 += __shfl_xor(s1, off2);
        s2 += __shfl_xor(s2, off2);
    }
    __shared__ float red[8];
    int wid = t >> 6, lid = t & 63;
    if (lid == 0) { red[wid] = s1; red[4 + wid] = s2; }
    __syncthreads();
    s1 = red[0] + red[1] + red[2] + red[3];
    s2 = red[4] + red[5] + red[6] + red[7];

    float mu   = s1 * (1.f / DM);
    float var  = s2 * (1.f / DM) - mu * mu;
    float rstd = rsqrtf(var + 1e-5f);

    float4 gv = *(const float4*)(g + (t << 2));
    float4 bv = *(const float4*)(b + (t << 2));
    float4 ov;
    ov.x = (v.x - mu) * rstd * gv.x + bv.x;
    ov.y = (v.y - mu) * rstd * gv.y + bv.y;
    ov.z = (v.z - mu) * rstd * gv.z + bv.z;
    ov.w = (v.w - mu) * rstd * gv.w + bv.w;
    if (out32) *(float4*)(out32 + off) = ov;
    if (out16) {
        ushort4 o;
        o.x = f2bfu(ov.x); o.y = f2bfu(ov.y); o.z = f2bfu(ov.z); o.w = f2bfu(ov.w);
        *(ushort4*)((unsigned short*)out16 + off) = o;
    }
}

// ---------------------------------------------------------------------------
extern "C" void kernel_launch(void* const* d_in, const int* in_sizes, int n_in,
                              void* d_out, int out_size, void* d_ws, size_t ws_size,
                              hipStream_t stream)
{
    const float* x       = (const float*)d_in[0];
    const float* q_in_w  = (const float*)d_in[1];
    const float* q_in_b  = (const float*)d_in[2];
    const float* k_in_w  = (const float*)d_in[3];
    const float* k_in_b  = (const float*)d_in[4];
    const float* v_in_w  = (const float*)d_in[5];
    const float* v_in_b  = (const float*)d_in[6];
    const float* out_w   = (const float*)d_in[7];
    const float* out_b   = (const float*)d_in[8];
    const float* ffn1_w  = (const float*)d_in[9];
    const float* ffn1_b  = (const float*)d_in[10];
    const float* ffn2_w  = (const float*)d_in[11];
    const float* ffn2_b  = (const float*)d_in[12];
    const float* n1_g    = (const float*)d_in[13];
    const float* n1_b    = (const float*)d_in[14];
    const float* n2_g    = (const float*)d_in[15];
    const float* n2_b    = (const float*)d_in[16];
    const float* q_out_w = (const float*)d_in[17];
    const float* q_out_b = (const float*)d_in[18];
    const float* k_out_w = (const float*)d_in[19];
    const float* k_out_b = (const float*)d_in[20];
    const float* v_out_w = (const float*)d_in[21];
    const float* v_out_b = (const float*)d_in[22];

    float* out = (float*)d_out;
    const long SD = (long)SEQ * DM;
    const long MB = 1024 * 1024;

    // --- workspace layout, 48 MiB, lifetime-checked ---
    // [0,4)   xbf (conv1->in-proj); lpart [0,.5) (attn->reduce); h32 [0,8) after
    // [4,8)   qb (in-proj->attn); h32 part
    // [8,12)  kb; h16 (ln1->FFN1); P2 part
    // [12,16) vb; P2 part              P2 = [8,24) fp32 16MB (FFN2->ln2)
    // [16,20) atnb (reduce->out-proj); P2 part
    // [20,36) Opart (attn->reduce); P1 16MB (out-proj->ln1); f1 part
    // [24,40) f1 bf16 16MB (FFN1->FFN2); then wqo[24,26) wko[26,28) wvo[28,30), ybf[30,34)
    // [32,34) wqi, [34,36) wki (conv1->in-proj, dead before Opart)
    // [36,38) wvi; [38,40) wo (conv1->out-proj, dead before f1)
    // [40,48) wf1 (conv1->FFN1); wf2 (conv2->FFN2)
    char* w = (char*)d_ws;
    bf16*  xbf   = (bf16*)(w);
    float* lpart = (float*)(w);
    bf16*  qb    = (bf16*)(w + 4  * MB);
    bf16*  kb    = (bf16*)(w + 8  * MB);
    bf16*  vb    = (bf16*)(w + 12 * MB);
    bf16*  atnb  = (bf16*)(w + 16 * MB);
    float* h32   = (float*)(w);
    bf16*  h16   = (bf16*)(w + 8  * MB);
    float* P2    = (float*)(w + 8  * MB);
    bf16*  Opart = (bf16*)(w + 20 * MB);
    float* P1    = (float*)(w + 20 * MB);
    bf16*  f1    = (bf16*)(w + 24 * MB);
    bf16*  wqi   = (bf16*)(w + 32 * MB);
    bf16*  wki   = (bf16*)(w + 34 * MB);
    bf16*  wvi   = (bf16*)(w + 36 * MB);
    bf16*  wo    = (bf16*)(w + 38 * MB);
    bf16*  wf1   = (bf16*)(w + 40 * MB);
    bf16*  wf2   = (bf16*)(w + 40 * MB);
    bf16*  wqo   = (bf16*)(w + 24 * MB);
    bf16*  wko   = (bf16*)(w + 26 * MB);
    bf16*  wvo   = (bf16*)(w + 28 * MB);
    bf16*  ybf   = (bf16*)(w + 30 * MB);
    float* y32   = out + 3 * SD;

    dim3 blk(256);
    const int DD = DM * DM;

    // --- conv group 1: x + in/out-proj weights + ffn1 ---
    {
        ConvSegs cs;
        cs.s[0] = {x,      xbf, (int)SD};
        cs.s[1] = {q_in_w, wqi, DD};
        cs.s[2] = {k_in_w, wki, DD};
        cs.s[3] = {v_in_w, wvi, DD};
        cs.s[4] = {out_w,  wo,  DD};
        cs.s[5] = {ffn1_w, wf1, DM * DFF};
        conv_multi_k<<<dim3(DM * DFF / 1024, 6), blk, 0, stream>>>(cs);
    }

    // --- q/k/v in-projections (128x64, 768 blocks) ---
    {
        GemmPtrs p{};
        p.W[0] = wqi; p.W[1] = wki; p.W[2] = wvi;
        p.bias[0] = q_in_b; p.bias[1] = k_in_b; p.bias[2] = v_in_b;
        p.out16[0] = qb; p.out16[1] = kb; p.out16[2] = vb;
        gemm_bf16_k<128, 64><<<dim3(DM / 64, SEQ / 128, 3), blk, 0, stream>>>(
            xbf, p, DM, DM, 0);
    }

    // --- attention: kv-split x4 (2048 blocks) + reduce ---
    attn_mfma_k<<<dim3(SEQ / 64, NH, KVSPLIT), blk, 0, stream>>>(
        qb, kb, vb, Opart, lpart);
    attn_reduce_k<<<dim3((int)(SD / 2048)), blk, 0, stream>>>(Opart, lpart, atnb);

    // --- out-projection, split-K=2 (64x128, 512 blocks) -> P1 ---
    gemm_splitk_k<64, 128, 2><<<dim3(DM / 128, SEQ / 64, 2), blk, 0, stream>>>(
        atnb, wo, P1, DM, DM);

    // --- LN1 fused reduce: h = LN(x + P1 + out_b) ---
    ln_red_k<2><<<SEQ, blk, 0, stream>>>(P1, out_b, x, n1_g, n1_b, h32, h16);

    // --- FFN1 (128x64, 1024 blocks, relu) ---
    {
        GemmPtrs p{};
        p.W[0] = wf1; p.bias[0] = ffn1_b; p.out16[0] = f1;
        gemm_bf16_k<128, 64><<<dim3(DFF / 64, SEQ / 128, 1), blk, 0, stream>>>(
            h16, p, DFF, DM, 1);
    }

    // --- conv wf2 (into dead wf1 region) ---
    conv_k<<<dim3(DM * DFF / 1024), blk, 0, stream>>>(ffn2_w, wf2, DM * DFF);

    // --- FFN2, split-K=2 (64x128, 512 blocks) -> P2 ---
    gemm_splitk_k<64, 128, 2><<<dim3(DM / 128, SEQ / 64, 2), blk, 0, stream>>>(
        f1, wf2, P2, DM, DFF);

    // --- conv group 3 (into dead f1 region) ---
    {
        ConvSegs cs;
        cs.s[0] = {q_out_w, wqo, DD};
        cs.s[1] = {k_out_w, wko, DD};
        cs.s[2] = {v_out_w, wvo, DD};
        cs.s[3] = cs.s[0]; cs.s[4] = cs.s[0]; cs.s[5] = cs.s[0];
        conv_multi_k<<<dim3(DD / 1024, 3), blk, 0, stream>>>(cs);
    }

    // --- LN2 fused reduce: y = LN(h + P2 + ffn2_b) ---
    ln_red_k<2><<<SEQ, blk, 0, stream>>>(P2, ffn2_b, h32, n2_g, n2_b, y32, ybf);

    // --- next-layer projections (128x64, 768 blocks) ---
    {
        GemmPtrs p{};
        p.W[0] = wqo; p.W[1] = wko; p.W[2] = wvo;
        p.bias[0] = q_out_b; p.bias[1] = k_out_b; p.bias[2] = v_out_b;
        p.out32[0] = out; p.out32[1] = out + SD; p.out32[2] = out + 2 * SD;
        gemm_bf16_k<128, 64><<<dim3(DM / 64, SEQ / 128, 3), blk, 0, stream>>>(
            ybf, p, DM, DM, 0);
    }
}